// Round 13
// baseline (355.615 us; speedup 1.0000x reference)
//
#include <hip/hip_runtime.h>
#include <hip/hip_bf16.h>

// Problem constants
#define BATCH   2
#define SEQ     1024
#define DMODEL  1024
#define DINNER  2048
#define DSTATE  16
#define DTRANK  64
#define DCONV   4
#define NLAYERS 2
#define ROWS    (BATCH*SEQ)        // 2048 (b,l) rows
#define NCHUNK  32
#define CHUNK   32                 // SEQ / NCHUNK
#define KSPLIT  8
#define KSLICE  (DINNER / KSPLIT)  // 256  (x_proj)
#define KSO     4
#define KSLICE_O (DINNER / KSO)    // 512  (out_proj)
#define KSI     2
#define KSLICE_I (DMODEL / KSI)    // 512  (in_proj)
#define LOG2E   1.44269504088896f

typedef unsigned short ushort_t;
typedef __attribute__((ext_vector_type(8))) short short8;
typedef __attribute__((ext_vector_type(4))) float f32x4;

// fp32 -> bf16 round-to-nearest-even
__device__ __forceinline__ ushort_t f2bf(float f) {
  union { float f; unsigned u; } v; v.f = f;
  unsigned r = v.u + 0x7fffu + ((v.u >> 16) & 1u);
  return (ushort_t)(r >> 16);
}
__device__ __forceinline__ float bf2f(ushort_t h) {
  union { unsigned u; float f; } v; v.u = ((unsigned)h) << 16;
  return v.f;
}

// async global->LDS 16B
__device__ __forceinline__ void g2lds16(const ushort_t* g, ushort_t* l) {
  __builtin_amdgcn_global_load_lds(
      (const __attribute__((address_space(1))) void*)g,
      (__attribute__((address_space(3))) void*)l, 16, 0, 0);
}

// XCD-aware bijective block swizzle (requires gridDim.x*gridDim.y % 8 == 0).
__device__ __forceinline__ void xcd_swz(int& bx, int& by) {
  const int nx = gridDim.x, nwg = nx * gridDim.y;
  int id = by * nx + bx;
  const int q = nwg >> 3;
  id = (id & 7) * q + (id >> 3);
  bx = id % nx; by = id / nx;
}

// LDS quarter-swizzle (store quarter q of row r at q ^ ((r>>1)&3)):
#define STG_Q(tid) (((tid) & 3) ^ (((tid) >> 3) & 3))
#define LDQ(lane)  ((((lane) >> 4) ^ (((lane) >> 1) & 3)) * 8)

// ---------------------------------------------------------------------------
// cast fp32 -> bf16, 4 elems/thread
__global__ __launch_bounds__(256) void cast_bf16_kernel(
    const float* __restrict__ in, ushort_t* __restrict__ out)
{
  const int i = blockIdx.x * 256 + threadIdx.x;
  const float4 v = reinterpret_cast<const float4*>(in)[i];
  ushort4 o;
  o.x = f2bf(v.x); o.y = f2bf(v.y); o.z = f2bf(v.z); o.w = f2bf(v.w);
  reinterpret_cast<ushort4*>(out)[i] = o;
}

// ---------------------------------------------------------------------------
// init: out = x; h16 = bf16(rms(x) * w).  One block per row, 4 elems/thread.
__global__ __launch_bounds__(256) void init_rms_kernel(
    const float* __restrict__ x, const float* __restrict__ w,
    float* __restrict__ out, ushort_t* __restrict__ h16)
{
  const int row = blockIdx.x, t = threadIdx.x;
  const size_t base = (size_t)row * DMODEL + 4 * t;
  const float4 s = *reinterpret_cast<const float4*>(&x[base]);
  *reinterpret_cast<float4*>(&out[base]) = s;
  float ss = s.x * s.x + s.y * s.y + s.z * s.z + s.w * s.w;
  #pragma unroll
  for (int m = 1; m < 64; m <<= 1) ss += __shfl_xor(ss, m);
  __shared__ float red[4];
  if ((t & 63) == 0) red[t >> 6] = ss;
  __syncthreads();
  const float tot = red[0] + red[1] + red[2] + red[3];
  const float scale = rsqrtf(tot * (1.f / DMODEL) + 1e-5f);
  const float4 w4 = *reinterpret_cast<const float4*>(&w[4 * t]);
  ushort4 o;
  o.x = f2bf(s.x * scale * w4.x); o.y = f2bf(s.y * scale * w4.y);
  o.z = f2bf(s.z * scale * w4.z); o.w = f2bf(s.w * scale * w4.w);
  *reinterpret_cast<ushort4*>(&h16[base]) = o;
}

// ---------------------------------------------------------------------------
// bf16 MFMA GEMM (dt_proj): D = A @ B^T, C2 = bf16(softplus(acc + bias[col])).
__global__ __launch_bounds__(256) void gemm_dtproj_kernel(
    const ushort_t* __restrict__ A, const ushort_t* __restrict__ B,
    ushort_t* __restrict__ C2, const float* __restrict__ bias,
    int K, int lda, int ldb, int ldc)
{
  __shared__ __align__(16) ushort_t As[128 * 32];
  __shared__ __align__(16) ushort_t Bs[128 * 32];
  const int tid = threadIdx.x;
  const int lane = tid & 63, wid = tid >> 6;
  const int wr = wid >> 1, wc = wid & 1;
  int bx = blockIdx.x, by = blockIdx.y;
  xcd_swz(bx, by);
  const int row0 = by * 128, col0 = bx * 128;

  const int sq = STG_Q(tid) * 8;
  const ushort_t* ga0 = A + (size_t)(row0 + (tid >> 2)) * lda + sq;
  const ushort_t* ga1 = A + (size_t)(row0 + 64 + (tid >> 2)) * lda + sq;
  const ushort_t* gb0 = B + (size_t)(col0 + (tid >> 2)) * ldb + sq;
  const ushort_t* gb1 = B + (size_t)(col0 + 64 + (tid >> 2)) * ldb + sq;
  ushort_t* la0 = &As[tid * 8];
  ushort_t* la1 = &As[(256 + tid) * 8];
  ushort_t* lb0 = &Bs[tid * 8];
  ushort_t* lb1 = &Bs[(256 + tid) * 8];

  const int lk = LDQ(lane);
  const int lr16 = lane & 15;

  f32x4 acc[4][4] = {};

  for (int kb = 0; kb < K; kb += 32) {
    g2lds16(ga0 + kb, la0);
    g2lds16(ga1 + kb, la1);
    g2lds16(gb0 + kb, lb0);
    g2lds16(gb1 + kb, lb1);
    __syncthreads();

    short8 af[4], bfr[4];
    #pragma unroll
    for (int i = 0; i < 4; ++i)
      af[i] = *reinterpret_cast<const short8*>(
          &As[(wr * 64 + i * 16 + lr16) * 32 + lk]);
    #pragma unroll
    for (int j = 0; j < 4; ++j)
      bfr[j] = *reinterpret_cast<const short8*>(
          &Bs[(wc * 64 + j * 16 + lr16) * 32 + lk]);
    #pragma unroll
    for (int i = 0; i < 4; ++i)
      #pragma unroll
      for (int j = 0; j < 4; ++j)
        acc[i][j] = __builtin_amdgcn_mfma_f32_16x16x32_bf16(
            af[i], bfr[j], acc[i][j], 0, 0, 0);
    __syncthreads();
  }

  // C/D layout: col = lane&15, row = (lane>>4)*4 + reg
  const int cr = (lane >> 4) * 4;
  #pragma unroll
  for (int i = 0; i < 4; ++i) {
    #pragma unroll
    for (int j = 0; j < 4; ++j) {
      const int col = col0 + wc * 64 + j * 16 + lr16;
      #pragma unroll
      for (int r = 0; r < 4; ++r) {
        const int row = row0 + wr * 64 + i * 16 + cr + r;
        float v = acc[i][j][r] + bias[col];
        v = (v > 20.f) ? v : log1pf(__expf(v));
        C2[(size_t)row * ldc + col] = f2bf(v);
      }
    }
  }
}

// ---------------------------------------------------------------------------
// Generic split-K bf16 GEMM: partial[z] = A[:, z*KS : (z+1)*KS] @ B^T slice.
// A (M x ldk-total), B (N x ldk-total), output slab stride = ROWS*ldc.
template<int KS>
__global__ __launch_bounds__(256) void splitk_gemm_kernel(
    const ushort_t* __restrict__ A, const ushort_t* __restrict__ B,
    ushort_t* __restrict__ partial, int ldk, int ldc)
{
  __shared__ __align__(16) ushort_t As[128 * 32];
  __shared__ __align__(16) ushort_t Bs[128 * 32];
  const int tid = threadIdx.x;
  const int lane = tid & 63, wid = tid >> 6;
  const int wr = wid >> 1, wc = wid & 1;
  int bx = blockIdx.x, by = blockIdx.y;
  xcd_swz(bx, by);
  const int row0 = by * 128, col0 = bx * 128;
  const int k0 = blockIdx.z * KS;

  const int sq = STG_Q(tid) * 8;
  const ushort_t* ga0 = A + (size_t)(row0 + (tid >> 2)) * ldk + k0 + sq;
  const ushort_t* ga1 = A + (size_t)(row0 + 64 + (tid >> 2)) * ldk + k0 + sq;
  const ushort_t* gb0 = B + (size_t)(col0 + (tid >> 2)) * ldk + k0 + sq;
  const ushort_t* gb1 = B + (size_t)(col0 + 64 + (tid >> 2)) * ldk + k0 + sq;
  ushort_t* la0 = &As[tid * 8];
  ushort_t* la1 = &As[(256 + tid) * 8];
  ushort_t* lb0 = &Bs[tid * 8];
  ushort_t* lb1 = &Bs[(256 + tid) * 8];

  const int lk = LDQ(lane);
  const int lr16 = lane & 15;

  f32x4 acc[4][4] = {};

  for (int kb = 0; kb < KS; kb += 32) {
    g2lds16(ga0 + kb, la0);
    g2lds16(ga1 + kb, la1);
    g2lds16(gb0 + kb, lb0);
    g2lds16(gb1 + kb, lb1);
    __syncthreads();

    short8 af[4], bfr[4];
    #pragma unroll
    for (int i = 0; i < 4; ++i)
      af[i] = *reinterpret_cast<const short8*>(
          &As[(wr * 64 + i * 16 + lr16) * 32 + lk]);
    #pragma unroll
    for (int j = 0; j < 4; ++j)
      bfr[j] = *reinterpret_cast<const short8*>(
          &Bs[(wc * 64 + j * 16 + lr16) * 32 + lk]);
    #pragma unroll
    for (int i = 0; i < 4; ++i)
      #pragma unroll
      for (int j = 0; j < 4; ++j)
        acc[i][j] = __builtin_amdgcn_mfma_f32_16x16x32_bf16(
            af[i], bfr[j], acc[i][j], 0, 0, 0);
    __syncthreads();
  }

  ushort_t* Cz = partial + (size_t)blockIdx.z * ROWS * ldc;
  const int cr = (lane >> 4) * 4;
  #pragma unroll
  for (int i = 0; i < 4; ++i) {
    #pragma unroll
    for (int j = 0; j < 4; ++j) {
      const int col = col0 + wc * 64 + j * 16 + lr16;
      #pragma unroll
      for (int r = 0; r < 4; ++r) {
        const int row = row0 + wr * 64 + i * 16 + cr + r;
        Cz[(size_t)row * ldc + col] = f2bf(acc[i][j][r]);
      }
    }
  }
}

// ---------------------------------------------------------------------------
// out += sum_z partial[z]; if RMS, also emit h16 = bf16(rms(out_row) * nw).
template<bool RMS>
__global__ __launch_bounds__(256) void outproj_reduce_rms_kernel(
    const ushort_t* __restrict__ partial, const float* __restrict__ nw,
    float* __restrict__ out, ushort_t* __restrict__ h16)
{
  const int row = blockIdx.x, t = threadIdx.x;
  const size_t base = (size_t)row * DMODEL + 4 * t;
  float4 s = *reinterpret_cast<float4*>(&out[base]);
  #pragma unroll
  for (int z = 0; z < KSO; ++z) {
    const ushort4 p = *reinterpret_cast<const ushort4*>(
        &partial[(size_t)z * ROWS * DMODEL + base]);
    s.x += bf2f(p.x); s.y += bf2f(p.y); s.z += bf2f(p.z); s.w += bf2f(p.w);
  }
  *reinterpret_cast<float4*>(&out[base]) = s;
  if (RMS) {
    float ss = s.x * s.x + s.y * s.y + s.z * s.z + s.w * s.w;
    #pragma unroll
    for (int m = 1; m < 64; m <<= 1) ss += __shfl_xor(ss, m);
    __shared__ float red[4];
    if ((t & 63) == 0) red[t >> 6] = ss;
    __syncthreads();
    const float tot = red[0] + red[1] + red[2] + red[3];
    const float scale = rsqrtf(tot * (1.f / DMODEL) + 1e-5f);
    const float4 w4 = *reinterpret_cast<const float4*>(&nw[4 * t]);
    ushort4 o;
    o.x = f2bf(s.x * scale * w4.x); o.y = f2bf(s.y * scale * w4.y);
    o.z = f2bf(s.z * scale * w4.z); o.w = f2bf(s.w * scale * w4.w);
    *reinterpret_cast<ushort4*>(&h16[base]) = o;
  }
}

// ---------------------------------------------------------------------------
// x_proj MFMA split-K: partial[kz] = xc16 @ xpw16^T over K slice kz (bf16).
__global__ __launch_bounds__(256) void xproj_mfma_kernel(
    const ushort_t* __restrict__ A,    // (ROWS, DINNER) bf16 xc
    const ushort_t* __restrict__ B,    // (96, DINNER) bf16 xpw
    ushort_t* __restrict__ partial)    // (KSPLIT, ROWS, 96) bf16
{
  __shared__ __align__(16) ushort_t As[128 * 32];
  __shared__ __align__(16) ushort_t Bs[96 * 32];
  const int tid = threadIdx.x;
  const int lane = tid & 63, wid = tid >> 6;
  int bx = blockIdx.x, by = blockIdx.y;
  xcd_swz(bx, by);
  const int kz = bx, row0 = by * 128;
  const int k0 = kz * KSLICE;

  const int sq = STG_Q(tid) * 8;
  const ushort_t* ga0 = A + (size_t)(row0 + (tid >> 2)) * DINNER + k0 + sq;
  const ushort_t* ga1 = A + (size_t)(row0 + 64 + (tid >> 2)) * DINNER + k0 + sq;
  const ushort_t* gb0 = B + (size_t)(tid >> 2) * DINNER + k0 + sq;
  const ushort_t* gb1 = B + (size_t)(64 + (tid >> 2)) * DINNER + k0 + sq; // tid<128
  ushort_t* la0 = &As[tid * 8];
  ushort_t* la1 = &As[(256 + tid) * 8];
  ushort_t* lb0 = &Bs[tid * 8];
  ushort_t* lb1 = &Bs[(256 + tid) * 8];                                  // tid<128

  const int lk = LDQ(lane);
  const int lr16 = lane & 15;

  f32x4 acc[2][6] = {};

  for (int kb = 0; kb < KSLICE; kb += 32) {
    g2lds16(ga0 + kb, la0);
    g2lds16(ga1 + kb, la1);
    g2lds16(gb0 + kb, lb0);
    if (tid < 128) g2lds16(gb1 + kb, lb1);   // rows 64..95 of B
    __syncthreads();

    short8 af[2], bfr[6];
    #pragma unroll
    for (int i = 0; i < 2; ++i)
      af[i] = *reinterpret_cast<const short8*>(
          &As[(wid * 32 + i * 16 + lr16) * 32 + lk]);
    #pragma unroll
    for (int j = 0; j < 6; ++j)
      bfr[j] = *reinterpret_cast<const short8*>(
          &Bs[(j * 16 + lr16) * 32 + lk]);
    #pragma unroll
    for (int i = 0; i < 2; ++i)
      #pragma unroll
      for (int j = 0; j < 6; ++j)
        acc[i][j] = __builtin_amdgcn_mfma_f32_16x16x32_bf16(
            af[i], bfr[j], acc[i][j], 0, 0, 0);
    __syncthreads();
  }

  const int cr = (lane >> 4) * 4;
  #pragma unroll
  for (int i = 0; i < 2; ++i) {
    #pragma unroll
    for (int j = 0; j < 6; ++j) {
      const int col = j * 16 + lr16;
      #pragma unroll
      for (int r = 0; r < 4; ++r) {
        const int row = row0 + wid * 32 + i * 16 + cr + r;
        partial[((size_t)kz * ROWS + row) * 96 + col] = f2bf(acc[i][j][r]);
      }
    }
  }
}

// ---------------------------------------------------------------------------
// x_proj reduce: sum KSPLIT bf16 partials.  cols 0..63 -> bf16 dl16;
// cols 64..95 -> fp32 dbcBC[row][32] (B,C for scan).
__global__ __launch_bounds__(256) void xproj_reduce_kernel(
    const ushort_t* __restrict__ partial, float* __restrict__ dbcBC,
    ushort_t* __restrict__ dl16)
{
  const int idx = blockIdx.x * 256 + threadIdx.x;   // < ROWS*96
  const int row = idx / 96, j = idx % 96;
  float s = 0.f;
  #pragma unroll
  for (int z = 0; z < KSPLIT; ++z)
    s += bf2f(partial[(size_t)z * ROWS * 96 + idx]);
  if (j < DTRANK) dl16[row * DTRANK + j] = f2bf(s);
  else            dbcBC[row * 32 + (j - DTRANK)] = s;
}

// ---------------------------------------------------------------------------
// Depthwise causal conv (k=4) + bias + SiLU over the two in_proj partial
// slabs (xc = p0+p1 summed inline); 8 channels/thread.
__global__ __launch_bounds__(256) void conv_silu_kernel(
    const ushort_t* __restrict__ pI,    // (KSI, ROWS, 2*DINNER) bf16 partials
    const float* __restrict__ cw, const float* __restrict__ cb,
    ushort_t* __restrict__ xc16)        // (ROWS, DINNER)
{
  const size_t SLAB = (size_t)ROWS * 2 * DINNER;
  const int idx = blockIdx.x * 256 + threadIdx.x;  // over ROWS*DINNER/8
  const int e0 = (idx * 8) % DINNER;
  const int bl = (idx * 8) / DINNER;
  const int l  = bl % SEQ;
  float acc[8];
  #pragma unroll
  for (int j = 0; j < 8; ++j) acc[j] = cb[e0 + j];
  float4 w4[8];
  #pragma unroll
  for (int j = 0; j < 8; ++j)
    w4[j] = *reinterpret_cast<const float4*>(&cw[(e0 + j) * DCONV]);
  #pragma unroll
  for (int k = 0; k < DCONV; ++k) {
    const int lk = l + k - (DCONV - 1);
    if (lk >= 0) {
      const size_t o = (size_t)(bl + k - (DCONV - 1)) * (2 * DINNER) + e0;
      const short8 v0 = *reinterpret_cast<const short8*>(&pI[o]);
      const short8 v1 = *reinterpret_cast<const short8*>(&pI[o + SLAB]);
      #pragma unroll
      for (int j = 0; j < 8; ++j) {
        const float wv = (k == 0) ? w4[j].x : (k == 1) ? w4[j].y
                        : (k == 2) ? w4[j].z : w4[j].w;
        acc[j] += (bf2f((ushort_t)v0[j]) + bf2f((ushort_t)v1[j])) * wv;
      }
    }
  }
  short8 o;
  #pragma unroll
  for (int j = 0; j < 8; ++j) {
    const float v = acc[j] / (1.f + __expf(-acc[j]));
    o[j] = (short)f2bf(v);
  }
  *reinterpret_cast<short8*>(&xc16[(size_t)bl * DINNER + e0]) = o;
}

// ---------------------------------------------------------------------------
// Pass A: lane-per-(b,c,e), 16 states in registers; exp2-folded decay.
__global__ __launch_bounds__(256) void scan_chunk_kernel(
    const ushort_t* __restrict__ d16,  // (ROWS, DINNER) softplus'd delta, bf16
    const ushort_t* __restrict__ xc16, // (ROWS, DINNER) bf16
    const float* __restrict__ dbcBC,   // (ROWS, 32): [0..16)=B
    const float* __restrict__ A_log,   // (DINNER, 16)
    ushort_t* __restrict__ P16,        // (BATCH, NCHUNK, DINNER, 16) bf16
    ushort_t* __restrict__ H16)        // (BATCH, NCHUNK, DINNER, 16) bf16
{
  __shared__ float sB[CHUNK][16];
  const int bc = blockIdx.y;               // b*NCHUNK + c
  const int b = bc / NCHUNK, c = bc % NCHUNK;
  const int e = blockIdx.x * 256 + threadIdx.x;
  const size_t row32 = ((size_t)b * SEQ + c * CHUNK) * 32;
  #pragma unroll
  for (int p = 0; p < (CHUNK * 16) / 256; ++p) {
    const int idx = threadIdx.x + p * 256;
    sB[idx >> 4][idx & 15] = dbcBC[row32 + (idx >> 4) * 32 + (idx & 15)];
  }
  float Aen[16];   // -exp(A_log) * log2(e)  (exp2-folded)
  #pragma unroll
  for (int q = 0; q < 4; ++q) {
    const float4 a4 = *reinterpret_cast<const float4*>(&A_log[(size_t)e * 16 + q * 4]);
    Aen[q * 4 + 0] = -__expf(a4.x) * LOG2E;
    Aen[q * 4 + 1] = -__expf(a4.y) * LOG2E;
    Aen[q * 4 + 2] = -__expf(a4.z) * LOG2E;
    Aen[q * 4 + 3] = -__expf(a4.w) * LOG2E;
  }
  __syncthreads();

  float h[16];
  #pragma unroll
  for (int n = 0; n < 16; ++n) h[n] = 0.f;
  float sd = 0.f;
  const size_t rowE = ((size_t)b * SEQ + c * CHUNK) * DINNER + e;
  float dv = bf2f(d16[rowE]), xv = bf2f(xc16[rowE]);
  for (int t = 0; t < CHUNK; ++t) {
    float dvn = 0.f, xvn = 0.f;
    if (t + 1 < CHUNK) {
      dvn = bf2f(d16[rowE + (size_t)(t + 1) * DINNER]);
      xvn = bf2f(xc16[rowE + (size_t)(t + 1) * DINNER]);
    }
    const float dxv = dv * xv;
    sd += dv;
    #pragma unroll
    for (int n = 0; n < 16; ++n) {
      const float dA = exp2f(dv * Aen[n]);
      h[n] = dA * h[n] + dxv * sB[t][n];
    }
    dv = dvn; xv = xvn;
  }
  const size_t o = ((size_t)bc * DINNER + e) * 16;
  #pragma unroll
  for (int q = 0; q < 4; ++q) {
    ushort4 pv, hv;
    pv.x = f2bf(exp2f(Aen[q * 4 + 0] * sd));
    pv.y = f2bf(exp2f(Aen[q * 4 + 1] * sd));
    pv.z = f2bf(exp2f(Aen[q * 4 + 2] * sd));
    pv.w = f2bf(exp2f(Aen[q * 4 + 3] * sd));
    hv.x = f2bf(h[q * 4 + 0]); hv.y = f2bf(h[q * 4 + 1]);
    hv.z = f2bf(h[q * 4 + 2]); hv.w = f2bf(h[q * 4 + 3]);
    *reinterpret_cast<ushort4*>(&P16[o + q * 4]) = pv;
    *reinterpret_cast<ushort4*>(&H16[o + q * 4]) = hv;
  }
}

// ---------------------------------------------------------------------------
// Pass B: serial combine over NCHUNK summaries; one thread per (b,e,n).
__global__ __launch_bounds__(256) void scan_combine_kernel(
    const ushort_t* __restrict__ P16, ushort_t* __restrict__ H16)
{
  const int idx = blockIdx.x * 256 + threadIdx.x;   // b*(DINNER*16) + e*16 + n
  const int b = idx >> 15;
  const int en = idx & (DINNER * 16 - 1);
  const size_t base = (size_t)b * NCHUNK * DINNER * 16 + en;
  float H = 0.f;
  float P = bf2f(P16[base]), hf = bf2f(H16[base]);
  for (int c = 0; c < NCHUNK; ++c) {
    const size_t o = base + (size_t)c * DINNER * 16;
    float Pn = 0.f, hfn = 0.f;
    if (c + 1 < NCHUNK) {
      const size_t on = o + (size_t)DINNER * 16;
      Pn = bf2f(P16[on]); hfn = bf2f(H16[on]);
    }
    H16[o] = f2bf(H);
    H = P * H + hf;
    P = Pn; hf = hfn;
  }
}

// ---------------------------------------------------------------------------
// Pass C: seeded re-scan fused with C-dot, D skip, z gate (z = p0+p1 from the
// in_proj partial slabs) -> bf16 yz.
__global__ __launch_bounds__(256) void scan_out_kernel(
    const ushort_t* __restrict__ d16,  // (ROWS, DINNER) bf16
    const ushort_t* __restrict__ xc16, // (ROWS, DINNER) bf16
    const float* __restrict__ dbcBC,   // (ROWS, 32)
    const ushort_t* __restrict__ pI,   // (KSI, ROWS, 2*DINNER): z at col DINNER+e
    const float* __restrict__ A_log,   // (DINNER, 16)
    const float* __restrict__ Dp,      // (DINNER)
    const ushort_t* __restrict__ H16,  // [b][c][e][n] seeds (bf16)
    ushort_t* __restrict__ yz16)       // (ROWS, DINNER) bf16 out
{
  __shared__ float sB[CHUNK][16];
  __shared__ float sC[CHUNK][16];
  const size_t SLAB = (size_t)ROWS * 2 * DINNER;
  const int bc = blockIdx.y;
  const int b = bc / NCHUNK, c = bc % NCHUNK;
  const int e = blockIdx.x * 256 + threadIdx.x;
  const size_t row32 = ((size_t)b * SEQ + c * CHUNK) * 32;
  #pragma unroll
  for (int p = 0; p < (CHUNK * 32) / 256; ++p) {
    const int idx = threadIdx.x + p * 256;
    const int t = idx >> 5, j = idx & 31;
    const float v = dbcBC[row32 + t * 32 + j];
    if (j < 16) sB[t][j] = v; else sC[t][j - 16] = v;
  }
  float Aen[16];
  #pragma unroll
  for (int q = 0; q < 4; ++q) {
    const float4 a4 = *reinterpret_cast<const float4*>(&A_log[(size_t)e * 16 + q * 4]);
    Aen[q * 4 + 0] = -__expf(a4.x) * LOG2E;
    Aen[q * 4 + 1] = -__expf(a4.y) * LOG2E;
    Aen[q * 4 + 2] = -__expf(a4.z) * LOG2E;
    Aen[q * 4 + 3] = -__expf(a4.w) * LOG2E;
  }
  float h[16];
  const size_t oh = ((size_t)bc * DINNER + e) * 16;
  #pragma unroll
  for (int q = 0; q < 4; ++q) {
    const ushort4 hv = *reinterpret_cast<const ushort4*>(&H16[oh + q * 4]);
    h[q * 4 + 0] = bf2f(hv.x); h[q * 4 + 1] = bf2f(hv.y);
    h[q * 4 + 2] = bf2f(hv.z); h[q * 4 + 3] = bf2f(hv.w);
  }
  const float dpe = Dp[e];
  __syncthreads();

  const size_t rowE = ((size_t)b * SEQ + c * CHUNK) * DINNER + e;
  const size_t rowZ = ((size_t)b * SEQ + c * CHUNK) * (2 * DINNER) + DINNER + e;
  float dv = bf2f(d16[rowE]), xv = bf2f(xc16[rowE]);
  float zv = bf2f(pI[rowZ]) + bf2f(pI[rowZ + SLAB]);
  for (int t = 0; t < CHUNK; ++t) {
    float dvn = 0.f, xvn = 0.f, zvn = 0.f;
    if (t + 1 < CHUNK) {
      dvn = bf2f(d16[rowE + (size_t)(t + 1) * DINNER]);
      xvn = bf2f(xc16[rowE + (size_t)(t + 1) * DINNER]);
      const size_t zo = rowZ + (size_t)(t + 1) * (2 * DINNER);
      zvn = bf2f(pI[zo]) + bf2f(pI[zo + SLAB]);
    }
    const float dxv = dv * xv;
    float y = dpe * xv;
    #pragma unroll
    for (int n = 0; n < 16; ++n) {
      const float dA = exp2f(dv * Aen[n]);
      h[n] = dA * h[n] + dxv * sB[t][n];
      y += h[n] * sC[t][n];
    }
    const float sz = zv / (1.f + __expf(-zv));
    yz16[rowE + (size_t)t * DINNER] = f2bf(y * sz);
    dv = dvn; xv = xvn; zv = zvn;
  }
}

// ---------------------------------------------------------------------------
extern "C" void kernel_launch(void* const* d_in, const int* in_sizes, int n_in,
                              void* d_out, int out_size, void* d_ws, size_t ws_size,
                              hipStream_t stream)
{
  const float* x         = (const float*)d_in[0];
  const float* norm_w    = (const float*)d_in[1];
  const float* in_proj_w = (const float*)d_in[2];
  const float* conv_w    = (const float*)d_in[3];
  const float* conv_b    = (const float*)d_in[4];
  const float* x_proj_w  = (const float*)d_in[5];
  const float* dt_proj_w = (const float*)d_in[6];
  const float* dt_proj_b = (const float*)d_in[7];
  const float* A_log     = (const float*)d_in[8];
  const float* D_param   = (const float*)d_in[9];
  const float* out_proj_w= (const float*)d_in[10];
  float* out = (float*)d_out;

  // Workspace (float offsets), total 24.25M floats = 97 MB of the 256 MB ws.
  // All regions DISJOINT except partO, which aliases partI slab0 (partI is
  // last read in scan_out step 8; partO written step 9, consumed step 10,
  // before next layer's step 1 rewrites partI).
  const size_t M = 1024 * 1024;
  float* ws = (float*)d_ws;
  ushort_t* w16i_all = (ushort_t*)ws;                 // [0,4M)    persistent
  ushort_t* w16o_all = (ushort_t*)(ws + 4 * M);       // [4M,6M)   persistent
  ushort_t* xpw16_all= (ushort_t*)(ws + 6 * M);       // 192K fl   persistent
  ushort_t* dtw16_all= (ushort_t*)(ws + 6 * M + 196608); // 128K fl persistent
  float* dbcBC    = ws + 6 * M + 327680;              // 64K fl
  ushort_t* dl16  = (ushort_t*)(ws + 6 * M + 393216); // 64K fl
  ushort_t* partI = (ushort_t*)(ws + 6 * M + 524288); // [6.5M,14.5M) 2 slabs
  ushort_t* partO = partI;                            // alias (time-disjoint)
  ushort_t* xc16  = (ushort_t*)(ws + 14 * M + 524288);// [14.5M,16.5M)
  ushort_t* d16   = (ushort_t*)(ws + 16 * M + 524288);// [16.5M,18.5M)
  ushort_t* P16   = (ushort_t*)(ws + 18 * M + 524288);// [18.5M,19.5M)
  ushort_t* H16   = (ushort_t*)(ws + 19 * M + 524288);// [19.5M,20.5M)
  ushort_t* yz16  = (ushort_t*)(ws + 20 * M + 524288);// [20.5M,22.5M)
  ushort_t* h16   = (ushort_t*)(ws + 22 * M + 524288);// [22.5M,23.5M)
  ushort_t* partX = (ushort_t*)(ws + 23 * M + 524288);// [23.5M,24.25M)

  // Upfront: cast ALL layers' weights to bf16 (weights are layer-contiguous).
  cast_bf16_kernel<<<NLAYERS * 2 * DINNER * DMODEL / 1024, 256, 0, stream>>>(
      in_proj_w, w16i_all);
  cast_bf16_kernel<<<NLAYERS * DMODEL * DINNER / 1024, 256, 0, stream>>>(
      out_proj_w, w16o_all);
  cast_bf16_kernel<<<NLAYERS * 96 * DINNER / 1024, 256, 0, stream>>>(
      x_proj_w, xpw16_all);
  cast_bf16_kernel<<<NLAYERS * DINNER * DTRANK / 1024, 256, 0, stream>>>(
      dt_proj_w, dtw16_all);

  // Init: residual = x, h16 = rms(x) * norm_w[0]
  init_rms_kernel<<<ROWS, 256, 0, stream>>>(x, norm_w, out, h16);

  for (int layer = 0; layer < NLAYERS; ++layer) {
    const float* cw  = conv_w     + (size_t)layer * DINNER * DCONV;
    const float* cb  = conv_b     + (size_t)layer * DINNER;
    const float* dtb = dt_proj_b  + (size_t)layer * DINNER;
    const float* Al  = A_log      + (size_t)layer * DINNER * DSTATE;
    const float* Dpp = D_param    + (size_t)layer * DINNER;
    const ushort_t* w16i  = w16i_all  + (size_t)layer * 2 * DINNER * DMODEL;
    const ushort_t* w16o  = w16o_all  + (size_t)layer * DMODEL * DINNER;
    const ushort_t* xpw16 = xpw16_all + (size_t)layer * 96 * DINNER;
    const ushort_t* dtw16 = dtw16_all + (size_t)layer * DINNER * DTRANK;

    // 1. in_proj split-K x2: partI[z] = h @ in_w^T (K slice z), bf16 slabs
    splitk_gemm_kernel<KSLICE_I>
        <<<dim3(2 * DINNER / 128, ROWS / 128, KSI), 256, 0, stream>>>(
            h16, w16i, partI, DMODEL, 2 * DINNER);

    // 2. xc16 = bf16(silu(causal_conv(p0+p1, cols<DINNER) + cb))
    conv_silu_kernel<<<(size_t)ROWS * DINNER / 8 / 256, 256, 0, stream>>>(
        partI, cw, cb, xc16);

    // 3+4. dbc = xc @ xpw^T  (bf16 MFMA split-K + reduce)
    xproj_mfma_kernel<<<dim3(KSPLIT, ROWS / 128), 256, 0, stream>>>(
        xc16, xpw16, partX);
    xproj_reduce_kernel<<<ROWS * 96 / 256, 256, 0, stream>>>(
        partX, dbcBC, dl16);

    // 5. delta = softplus(dl16 @ dtw^T + dtb) -> bf16 d16
    gemm_dtproj_kernel
        <<<dim3(DINNER / 128, ROWS / 128), 256, 0, stream>>>(
            dl16, dtw16, d16, dtb, DTRANK, DTRANK, DTRANK, DINNER);

    // 6-8. chunked selective scan + D skip + z gate -> yz16
    scan_chunk_kernel<<<dim3(DINNER / 256, BATCH * NCHUNK), 256, 0, stream>>>(
        d16, xc16, dbcBC, Al, P16, H16);
    scan_combine_kernel<<<BATCH * DINNER * 16 / 256, 256, 0, stream>>>(
        P16, H16);
    scan_out_kernel<<<dim3(DINNER / 256, BATCH * NCHUNK), 256, 0, stream>>>(
        d16, xc16, dbcBC, partI, Al, Dpp, H16, yz16);

    // 9. out_proj split-K (bf16 partials; partO aliases partI - now dead)
    splitk_gemm_kernel<KSLICE_O>
        <<<dim3(DMODEL / 128, ROWS / 128, KSO), 256, 0, stream>>>(
            yz16, w16o, partO, DINNER, DMODEL);

    // 10. residual += sum_z partO[z]; fuse next layer's rmsnorm
    if (layer + 1 < NLAYERS) {
      outproj_reduce_rms_kernel<true><<<ROWS, 256, 0, stream>>>(
          partO, norm_w + (size_t)(layer + 1) * DMODEL, out, h16);
    } else {
      outproj_reduce_rms_kernel<false><<<ROWS, 256, 0, stream>>>(
          partO, nullptr, out, nullptr);
    }
  }
}

// Round 14
// 347.728 us; speedup vs baseline: 1.0227x; 1.0227x over previous
//
#include <hip/hip_runtime.h>
#include <hip/hip_bf16.h>

// Problem constants
#define BATCH   2
#define SEQ     1024
#define DMODEL  1024
#define DINNER  2048
#define DSTATE  16
#define DTRANK  64
#define DCONV   4
#define NLAYERS 2
#define ROWS    (BATCH*SEQ)        // 2048 (b,l) rows
#define NCHUNK  32
#define CHUNK   32                 // SEQ / NCHUNK
#define KSPLIT  8
#define KSLICE  (DINNER / KSPLIT)  // 256  (x_proj)
#define KSO     4
#define KSLICE_O (DINNER / KSO)    // 512  (out_proj)
#define LOG2E   1.44269504088896f

typedef unsigned short ushort_t;
typedef __attribute__((ext_vector_type(8))) short short8;
typedef __attribute__((ext_vector_type(4))) float f32x4;

// fp32 -> bf16 round-to-nearest-even
__device__ __forceinline__ ushort_t f2bf(float f) {
  union { float f; unsigned u; } v; v.f = f;
  unsigned r = v.u + 0x7fffu + ((v.u >> 16) & 1u);
  return (ushort_t)(r >> 16);
}
__device__ __forceinline__ float bf2f(ushort_t h) {
  union { unsigned u; float f; } v; v.u = ((unsigned)h) << 16;
  return v.f;
}

// async global->LDS 16B
__device__ __forceinline__ void g2lds16(const ushort_t* g, ushort_t* l) {
  __builtin_amdgcn_global_load_lds(
      (const __attribute__((address_space(1))) void*)g,
      (__attribute__((address_space(3))) void*)l, 16, 0, 0);
}

// XCD-aware bijective block swizzle (requires gridDim.x*gridDim.y % 8 == 0).
__device__ __forceinline__ void xcd_swz(int& bx, int& by) {
  const int nx = gridDim.x, nwg = nx * gridDim.y;
  int id = by * nx + bx;
  const int q = nwg >> 3;
  id = (id & 7) * q + (id >> 3);
  bx = id % nx; by = id / nx;
}

// LDS quarter-swizzle (store quarter q of row r at q ^ ((r>>1)&3)):
#define STG_Q(tid) (((tid) & 3) ^ (((tid) >> 3) & 3))
#define LDQ(lane)  ((((lane) >> 4) ^ (((lane) >> 1) & 3)) * 8)

// ---------------------------------------------------------------------------
// cast fp32 -> bf16, 4 elems/thread
__global__ __launch_bounds__(256) void cast_bf16_kernel(
    const float* __restrict__ in, ushort_t* __restrict__ out)
{
  const int i = blockIdx.x * 256 + threadIdx.x;
  const float4 v = reinterpret_cast<const float4*>(in)[i];
  ushort4 o;
  o.x = f2bf(v.x); o.y = f2bf(v.y); o.z = f2bf(v.z); o.w = f2bf(v.w);
  reinterpret_cast<ushort4*>(out)[i] = o;
}

// ---------------------------------------------------------------------------
// init: out = x; h16 = bf16(rms(x) * w).  One block per row, 4 elems/thread.
__global__ __launch_bounds__(256) void init_rms_kernel(
    const float* __restrict__ x, const float* __restrict__ w,
    float* __restrict__ out, ushort_t* __restrict__ h16)
{
  const int row = blockIdx.x, t = threadIdx.x;
  const size_t base = (size_t)row * DMODEL + 4 * t;
  const float4 s = *reinterpret_cast<const float4*>(&x[base]);
  *reinterpret_cast<float4*>(&out[base]) = s;
  float ss = s.x * s.x + s.y * s.y + s.z * s.z + s.w * s.w;
  #pragma unroll
  for (int m = 1; m < 64; m <<= 1) ss += __shfl_xor(ss, m);
  __shared__ float red[4];
  if ((t & 63) == 0) red[t >> 6] = ss;
  __syncthreads();
  const float tot = red[0] + red[1] + red[2] + red[3];
  const float scale = rsqrtf(tot * (1.f / DMODEL) + 1e-5f);
  const float4 w4 = *reinterpret_cast<const float4*>(&w[4 * t]);
  ushort4 o;
  o.x = f2bf(s.x * scale * w4.x); o.y = f2bf(s.y * scale * w4.y);
  o.z = f2bf(s.z * scale * w4.z); o.w = f2bf(s.w * scale * w4.w);
  *reinterpret_cast<ushort4*>(&h16[base]) = o;
}

// ---------------------------------------------------------------------------
// bf16 MFMA GEMM: D[M][N] = A[M][K] * B[N][K]^T, bf16 output to C2.
// BM=BN=128, BK=32, 256 threads = 4 waves (2x2), 64x64 per wave.
// MODE 2: C2 = bf16(acc).  MODE 3: C2 = bf16(softplus(acc + bias[col])).
template<int MODE>
__global__ __launch_bounds__(256) void gemm_bf16_kernel(
    const ushort_t* __restrict__ A, const ushort_t* __restrict__ B,
    ushort_t* __restrict__ C2, const float* __restrict__ bias,
    int K, int lda, int ldb, int ldc)
{
  __shared__ __align__(16) ushort_t As[128 * 32];
  __shared__ __align__(16) ushort_t Bs[128 * 32];
  const int tid = threadIdx.x;
  const int lane = tid & 63, wid = tid >> 6;
  const int wr = wid >> 1, wc = wid & 1;
  int bx = blockIdx.x, by = blockIdx.y;
  xcd_swz(bx, by);
  const int row0 = by * 128, col0 = bx * 128;

  const int sq = STG_Q(tid) * 8;
  const ushort_t* ga0 = A + (size_t)(row0 + (tid >> 2)) * lda + sq;
  const ushort_t* ga1 = A + (size_t)(row0 + 64 + (tid >> 2)) * lda + sq;
  const ushort_t* gb0 = B + (size_t)(col0 + (tid >> 2)) * ldb + sq;
  const ushort_t* gb1 = B + (size_t)(col0 + 64 + (tid >> 2)) * ldb + sq;
  ushort_t* la0 = &As[tid * 8];
  ushort_t* la1 = &As[(256 + tid) * 8];
  ushort_t* lb0 = &Bs[tid * 8];
  ushort_t* lb1 = &Bs[(256 + tid) * 8];

  const int lk = LDQ(lane);
  const int lr16 = lane & 15;

  f32x4 acc[4][4] = {};

  for (int kb = 0; kb < K; kb += 32) {
    g2lds16(ga0 + kb, la0);
    g2lds16(ga1 + kb, la1);
    g2lds16(gb0 + kb, lb0);
    g2lds16(gb1 + kb, lb1);
    __syncthreads();

    short8 af[4], bfr[4];
    #pragma unroll
    for (int i = 0; i < 4; ++i)
      af[i] = *reinterpret_cast<const short8*>(
          &As[(wr * 64 + i * 16 + lr16) * 32 + lk]);
    #pragma unroll
    for (int j = 0; j < 4; ++j)
      bfr[j] = *reinterpret_cast<const short8*>(
          &Bs[(wc * 64 + j * 16 + lr16) * 32 + lk]);
    #pragma unroll
    for (int i = 0; i < 4; ++i)
      #pragma unroll
      for (int j = 0; j < 4; ++j)
        acc[i][j] = __builtin_amdgcn_mfma_f32_16x16x32_bf16(
            af[i], bfr[j], acc[i][j], 0, 0, 0);
    __syncthreads();
  }

  // C/D layout: col = lane&15, row = (lane>>4)*4 + reg
  const int cr = (lane >> 4) * 4;
  #pragma unroll
  for (int i = 0; i < 4; ++i) {
    #pragma unroll
    for (int j = 0; j < 4; ++j) {
      const int col = col0 + wc * 64 + j * 16 + lr16;
      #pragma unroll
      for (int r = 0; r < 4; ++r) {
        const int row = row0 + wr * 64 + i * 16 + cr + r;
        float v = acc[i][j][r];
        if (MODE == 3) {
          v += bias[col];
          v = (v > 20.f) ? v : log1pf(__expf(v));
        }
        C2[(size_t)row * ldc + col] = f2bf(v);
      }
    }
  }
}

// ---------------------------------------------------------------------------
// out_proj split-K: partial[z] = yz16 @ ow16^T over K slice z (bf16 partials).
__global__ __launch_bounds__(256) void outproj_splitk_kernel(
    const ushort_t* __restrict__ A,    // (ROWS, DINNER)
    const ushort_t* __restrict__ B,    // (DMODEL, DINNER)
    ushort_t* __restrict__ partial)    // (KSO, ROWS, DMODEL) bf16
{
  __shared__ __align__(16) ushort_t As[128 * 32];
  __shared__ __align__(16) ushort_t Bs[128 * 32];
  const int tid = threadIdx.x;
  const int lane = tid & 63, wid = tid >> 6;
  const int wr = wid >> 1, wc = wid & 1;
  int bx = blockIdx.x, by = blockIdx.y;
  xcd_swz(bx, by);
  const int row0 = by * 128, col0 = bx * 128;
  const int k0 = blockIdx.z * KSLICE_O;

  const int sq = STG_Q(tid) * 8;
  const ushort_t* ga0 = A + (size_t)(row0 + (tid >> 2)) * DINNER + k0 + sq;
  const ushort_t* ga1 = A + (size_t)(row0 + 64 + (tid >> 2)) * DINNER + k0 + sq;
  const ushort_t* gb0 = B + (size_t)(col0 + (tid >> 2)) * DINNER + k0 + sq;
  const ushort_t* gb1 = B + (size_t)(col0 + 64 + (tid >> 2)) * DINNER + k0 + sq;
  ushort_t* la0 = &As[tid * 8];
  ushort_t* la1 = &As[(256 + tid) * 8];
  ushort_t* lb0 = &Bs[tid * 8];
  ushort_t* lb1 = &Bs[(256 + tid) * 8];

  const int lk = LDQ(lane);
  const int lr16 = lane & 15;

  f32x4 acc[4][4] = {};

  for (int kb = 0; kb < KSLICE_O; kb += 32) {
    g2lds16(ga0 + kb, la0);
    g2lds16(ga1 + kb, la1);
    g2lds16(gb0 + kb, lb0);
    g2lds16(gb1 + kb, lb1);
    __syncthreads();

    short8 af[4], bfr[4];
    #pragma unroll
    for (int i = 0; i < 4; ++i)
      af[i] = *reinterpret_cast<const short8*>(
          &As[(wr * 64 + i * 16 + lr16) * 32 + lk]);
    #pragma unroll
    for (int j = 0; j < 4; ++j)
      bfr[j] = *reinterpret_cast<const short8*>(
          &Bs[(wc * 64 + j * 16 + lr16) * 32 + lk]);
    #pragma unroll
    for (int i = 0; i < 4; ++i)
      #pragma unroll
      for (int j = 0; j < 4; ++j)
        acc[i][j] = __builtin_amdgcn_mfma_f32_16x16x32_bf16(
            af[i], bfr[j], acc[i][j], 0, 0, 0);
    __syncthreads();
  }

  ushort_t* Cz = partial + (size_t)blockIdx.z * ROWS * DMODEL;
  const int cr = (lane >> 4) * 4;
  #pragma unroll
  for (int i = 0; i < 4; ++i) {
    #pragma unroll
    for (int j = 0; j < 4; ++j) {
      const int col = col0 + wc * 64 + j * 16 + lr16;
      #pragma unroll
      for (int r = 0; r < 4; ++r) {
        const int row = row0 + wr * 64 + i * 16 + cr + r;
        Cz[(size_t)row * DMODEL + col] = f2bf(acc[i][j][r]);
      }
    }
  }
}

// ---------------------------------------------------------------------------
// out += sum_z partial[z]; if RMS, also emit h16 = bf16(rms(out_row) * nw).
// One block per row (256 threads x 4 elems = DMODEL).
template<bool RMS>
__global__ __launch_bounds__(256) void outproj_reduce_rms_kernel(
    const ushort_t* __restrict__ partial, const float* __restrict__ nw,
    float* __restrict__ out, ushort_t* __restrict__ h16)
{
  const int row = blockIdx.x, t = threadIdx.x;
  const size_t base = (size_t)row * DMODEL + 4 * t;
  float4 s = *reinterpret_cast<float4*>(&out[base]);
  #pragma unroll
  for (int z = 0; z < KSO; ++z) {
    const ushort4 p = *reinterpret_cast<const ushort4*>(
        &partial[(size_t)z * ROWS * DMODEL + base]);
    s.x += bf2f(p.x); s.y += bf2f(p.y); s.z += bf2f(p.z); s.w += bf2f(p.w);
  }
  *reinterpret_cast<float4*>(&out[base]) = s;
  if (RMS) {
    float ss = s.x * s.x + s.y * s.y + s.z * s.z + s.w * s.w;
    #pragma unroll
    for (int m = 1; m < 64; m <<= 1) ss += __shfl_xor(ss, m);
    __shared__ float red[4];
    if ((t & 63) == 0) red[t >> 6] = ss;
    __syncthreads();
    const float tot = red[0] + red[1] + red[2] + red[3];
    const float scale = rsqrtf(tot * (1.f / DMODEL) + 1e-5f);
    const float4 w4 = *reinterpret_cast<const float4*>(&nw[4 * t]);
    ushort4 o;
    o.x = f2bf(s.x * scale * w4.x); o.y = f2bf(s.y * scale * w4.y);
    o.z = f2bf(s.z * scale * w4.z); o.w = f2bf(s.w * scale * w4.w);
    *reinterpret_cast<ushort4*>(&h16[base]) = o;
  }
}

// ---------------------------------------------------------------------------
// x_proj MFMA split-K: partial[kz] = xc16 @ xpw16^T over K slice kz (bf16).
__global__ __launch_bounds__(256) void xproj_mfma_kernel(
    const ushort_t* __restrict__ A,    // (ROWS, DINNER) bf16 xc
    const ushort_t* __restrict__ B,    // (96, DINNER) bf16 xpw
    ushort_t* __restrict__ partial)    // (KSPLIT, ROWS, 96) bf16
{
  __shared__ __align__(16) ushort_t As[128 * 32];
  __shared__ __align__(16) ushort_t Bs[96 * 32];
  const int tid = threadIdx.x;
  const int lane = tid & 63, wid = tid >> 6;
  int bx = blockIdx.x, by = blockIdx.y;
  xcd_swz(bx, by);
  const int kz = bx, row0 = by * 128;
  const int k0 = kz * KSLICE;

  const int sq = STG_Q(tid) * 8;
  const ushort_t* ga0 = A + (size_t)(row0 + (tid >> 2)) * DINNER + k0 + sq;
  const ushort_t* ga1 = A + (size_t)(row0 + 64 + (tid >> 2)) * DINNER + k0 + sq;
  const ushort_t* gb0 = B + (size_t)(tid >> 2) * DINNER + k0 + sq;
  const ushort_t* gb1 = B + (size_t)(64 + (tid >> 2)) * DINNER + k0 + sq; // tid<128
  ushort_t* la0 = &As[tid * 8];
  ushort_t* la1 = &As[(256 + tid) * 8];
  ushort_t* lb0 = &Bs[tid * 8];
  ushort_t* lb1 = &Bs[(256 + tid) * 8];                                  // tid<128

  const int lk = LDQ(lane);
  const int lr16 = lane & 15;

  f32x4 acc[2][6] = {};

  for (int kb = 0; kb < KSLICE; kb += 32) {
    g2lds16(ga0 + kb, la0);
    g2lds16(ga1 + kb, la1);
    g2lds16(gb0 + kb, lb0);
    if (tid < 128) g2lds16(gb1 + kb, lb1);   // rows 64..95 of B
    __syncthreads();

    short8 af[2], bfr[6];
    #pragma unroll
    for (int i = 0; i < 2; ++i)
      af[i] = *reinterpret_cast<const short8*>(
          &As[(wid * 32 + i * 16 + lr16) * 32 + lk]);
    #pragma unroll
    for (int j = 0; j < 6; ++j)
      bfr[j] = *reinterpret_cast<const short8*>(
          &Bs[(j * 16 + lr16) * 32 + lk]);
    #pragma unroll
    for (int i = 0; i < 2; ++i)
      #pragma unroll
      for (int j = 0; j < 6; ++j)
        acc[i][j] = __builtin_amdgcn_mfma_f32_16x16x32_bf16(
            af[i], bfr[j], acc[i][j], 0, 0, 0);
    __syncthreads();
  }

  const int cr = (lane >> 4) * 4;
  #pragma unroll
  for (int i = 0; i < 2; ++i) {
    #pragma unroll
    for (int j = 0; j < 6; ++j) {
      const int col = j * 16 + lr16;
      #pragma unroll
      for (int r = 0; r < 4; ++r) {
        const int row = row0 + wid * 32 + i * 16 + cr + r;
        partial[((size_t)kz * ROWS + row) * 96 + col] = f2bf(acc[i][j][r]);
      }
    }
  }
}

// ---------------------------------------------------------------------------
// x_proj reduce: sum KSPLIT bf16 partials.  cols 0..63 -> bf16 dl16;
// cols 64..95 -> fp32 dbcBC[row][32] (B,C for scan).
__global__ __launch_bounds__(256) void xproj_reduce_kernel(
    const ushort_t* __restrict__ partial, float* __restrict__ dbcBC,
    ushort_t* __restrict__ dl16)
{
  const int idx = blockIdx.x * 256 + threadIdx.x;   // < ROWS*96
  const int row = idx / 96, j = idx % 96;
  float s = 0.f;
  #pragma unroll
  for (int z = 0; z < KSPLIT; ++z)
    s += bf2f(partial[(size_t)z * ROWS * 96 + idx]);
  if (j < DTRANK) dl16[row * DTRANK + j] = f2bf(s);
  else            dbcBC[row * 32 + (j - DTRANK)] = s;
}

// ---------------------------------------------------------------------------
// Depthwise causal conv (k=4) + bias + SiLU over bf16 xz; 8 channels/thread.
__global__ __launch_bounds__(256) void conv_silu_kernel(
    const ushort_t* __restrict__ xz16,  // (ROWS, 2*DINNER) conv input = cols<DINNER
    const float* __restrict__ cw, const float* __restrict__ cb,
    ushort_t* __restrict__ xc16)        // (ROWS, DINNER)
{
  const int idx = blockIdx.x * 256 + threadIdx.x;  // over ROWS*DINNER/8
  const int e0 = (idx * 8) % DINNER;
  const int bl = (idx * 8) / DINNER;
  const int l  = bl % SEQ;
  float acc[8];
  #pragma unroll
  for (int j = 0; j < 8; ++j) acc[j] = cb[e0 + j];
  float4 w4[8];
  #pragma unroll
  for (int j = 0; j < 8; ++j)
    w4[j] = *reinterpret_cast<const float4*>(&cw[(e0 + j) * DCONV]);
  #pragma unroll
  for (int k = 0; k < DCONV; ++k) {
    const int lk = l + k - (DCONV - 1);
    if (lk >= 0) {
      const short8 v = *reinterpret_cast<const short8*>(
          &xz16[(size_t)(bl + k - (DCONV - 1)) * (2 * DINNER) + e0]);
      #pragma unroll
      for (int j = 0; j < 8; ++j) {
        const float wv = (k == 0) ? w4[j].x : (k == 1) ? w4[j].y
                        : (k == 2) ? w4[j].z : w4[j].w;
        acc[j] += bf2f((ushort_t)v[j]) * wv;
      }
    }
  }
  short8 o;
  #pragma unroll
  for (int j = 0; j < 8; ++j) {
    const float v = acc[j] / (1.f + __expf(-acc[j]));
    o[j] = (short)f2bf(v);
  }
  *reinterpret_cast<short8*>(&xc16[(size_t)bl * DINNER + e0]) = o;
}

// ---------------------------------------------------------------------------
// Pass A: lane-per-(b,c,e), 16 states in registers; exp2-folded decay.
__global__ __launch_bounds__(256) void scan_chunk_kernel(
    const ushort_t* __restrict__ d16,  // (ROWS, DINNER) softplus'd delta, bf16
    const ushort_t* __restrict__ xc16, // (ROWS, DINNER) bf16
    const float* __restrict__ dbcBC,   // (ROWS, 32): [0..16)=B
    const float* __restrict__ A_log,   // (DINNER, 16)
    ushort_t* __restrict__ P16,        // (BATCH, NCHUNK, DINNER, 16) bf16
    ushort_t* __restrict__ H16)        // (BATCH, NCHUNK, DINNER, 16) bf16
{
  __shared__ float sB[CHUNK][16];
  const int bc = blockIdx.y;               // b*NCHUNK + c
  const int b = bc / NCHUNK, c = bc % NCHUNK;
  const int e = blockIdx.x * 256 + threadIdx.x;
  const size_t row32 = ((size_t)b * SEQ + c * CHUNK) * 32;
  #pragma unroll
  for (int p = 0; p < (CHUNK * 16) / 256; ++p) {
    const int idx = threadIdx.x + p * 256;
    sB[idx >> 4][idx & 15] = dbcBC[row32 + (idx >> 4) * 32 + (idx & 15)];
  }
  float Aen[16];   // -exp(A_log) * log2(e)  (exp2-folded)
  #pragma unroll
  for (int q = 0; q < 4; ++q) {
    const float4 a4 = *reinterpret_cast<const float4*>(&A_log[(size_t)e * 16 + q * 4]);
    Aen[q * 4 + 0] = -__expf(a4.x) * LOG2E;
    Aen[q * 4 + 1] = -__expf(a4.y) * LOG2E;
    Aen[q * 4 + 2] = -__expf(a4.z) * LOG2E;
    Aen[q * 4 + 3] = -__expf(a4.w) * LOG2E;
  }
  __syncthreads();

  float h[16];
  #pragma unroll
  for (int n = 0; n < 16; ++n) h[n] = 0.f;
  float sd = 0.f;
  const size_t rowE = ((size_t)b * SEQ + c * CHUNK) * DINNER + e;
  float dv = bf2f(d16[rowE]), xv = bf2f(xc16[rowE]);
  for (int t = 0; t < CHUNK; ++t) {
    float dvn = 0.f, xvn = 0.f;
    if (t + 1 < CHUNK) {
      dvn = bf2f(d16[rowE + (size_t)(t + 1) * DINNER]);
      xvn = bf2f(xc16[rowE + (size_t)(t + 1) * DINNER]);
    }
    const float dxv = dv * xv;
    sd += dv;
    #pragma unroll
    for (int n = 0; n < 16; ++n) {
      const float dA = exp2f(dv * Aen[n]);
      h[n] = dA * h[n] + dxv * sB[t][n];
    }
    dv = dvn; xv = xvn;
  }
  const size_t o = ((size_t)bc * DINNER + e) * 16;
  #pragma unroll
  for (int q = 0; q < 4; ++q) {
    ushort4 pv, hv;
    pv.x = f2bf(exp2f(Aen[q * 4 + 0] * sd));
    pv.y = f2bf(exp2f(Aen[q * 4 + 1] * sd));
    pv.z = f2bf(exp2f(Aen[q * 4 + 2] * sd));
    pv.w = f2bf(exp2f(Aen[q * 4 + 3] * sd));
    hv.x = f2bf(h[q * 4 + 0]); hv.y = f2bf(h[q * 4 + 1]);
    hv.z = f2bf(h[q * 4 + 2]); hv.w = f2bf(h[q * 4 + 3]);
    *reinterpret_cast<ushort4*>(&P16[o + q * 4]) = pv;
    *reinterpret_cast<ushort4*>(&H16[o + q * 4]) = hv;
  }
}

// ---------------------------------------------------------------------------
// Pass B: serial combine over NCHUNK summaries; one thread per (b,e,n).
__global__ __launch_bounds__(256) void scan_combine_kernel(
    const ushort_t* __restrict__ P16, ushort_t* __restrict__ H16)
{
  const int idx = blockIdx.x * 256 + threadIdx.x;   // b*(DINNER*16) + e*16 + n
  const int b = idx >> 15;
  const int en = idx & (DINNER * 16 - 1);
  const size_t base = (size_t)b * NCHUNK * DINNER * 16 + en;
  float H = 0.f;
  float P = bf2f(P16[base]), hf = bf2f(H16[base]);
  for (int c = 0; c < NCHUNK; ++c) {
    const size_t o = base + (size_t)c * DINNER * 16;
    float Pn = 0.f, hfn = 0.f;
    if (c + 1 < NCHUNK) {
      const size_t on = o + (size_t)DINNER * 16;
      Pn = bf2f(P16[on]); hfn = bf2f(H16[on]);
    }
    H16[o] = f2bf(H);
    H = P * H + hf;
    P = Pn; hf = hfn;
  }
}

// ---------------------------------------------------------------------------
// Pass C: seeded re-scan fused with C-dot, D skip, z gate -> bf16 yz.
__global__ __launch_bounds__(256) void scan_out_kernel(
    const ushort_t* __restrict__ d16,  // (ROWS, DINNER) bf16
    const ushort_t* __restrict__ xc16, // (ROWS, DINNER) bf16
    const float* __restrict__ dbcBC,   // (ROWS, 32)
    const ushort_t* __restrict__ xz16, // (ROWS, 2*DINNER): z at col DINNER+e
    const float* __restrict__ A_log,   // (DINNER, 16)
    const float* __restrict__ Dp,      // (DINNER)
    const ushort_t* __restrict__ H16,  // [b][c][e][n] seeds (bf16)
    ushort_t* __restrict__ yz16)       // (ROWS, DINNER) bf16 out
{
  __shared__ float sB[CHUNK][16];
  __shared__ float sC[CHUNK][16];
  const int bc = blockIdx.y;
  const int b = bc / NCHUNK, c = bc % NCHUNK;
  const int e = blockIdx.x * 256 + threadIdx.x;
  const size_t row32 = ((size_t)b * SEQ + c * CHUNK) * 32;
  #pragma unroll
  for (int p = 0; p < (CHUNK * 32) / 256; ++p) {
    const int idx = threadIdx.x + p * 256;
    const int t = idx >> 5, j = idx & 31;
    const float v = dbcBC[row32 + t * 32 + j];
    if (j < 16) sB[t][j] = v; else sC[t][j - 16] = v;
  }
  float Aen[16];
  #pragma unroll
  for (int q = 0; q < 4; ++q) {
    const float4 a4 = *reinterpret_cast<const float4*>(&A_log[(size_t)e * 16 + q * 4]);
    Aen[q * 4 + 0] = -__expf(a4.x) * LOG2E;
    Aen[q * 4 + 1] = -__expf(a4.y) * LOG2E;
    Aen[q * 4 + 2] = -__expf(a4.z) * LOG2E;
    Aen[q * 4 + 3] = -__expf(a4.w) * LOG2E;
  }
  float h[16];
  const size_t oh = ((size_t)bc * DINNER + e) * 16;
  #pragma unroll
  for (int q = 0; q < 4; ++q) {
    const ushort4 hv = *reinterpret_cast<const ushort4*>(&H16[oh + q * 4]);
    h[q * 4 + 0] = bf2f(hv.x); h[q * 4 + 1] = bf2f(hv.y);
    h[q * 4 + 2] = bf2f(hv.z); h[q * 4 + 3] = bf2f(hv.w);
  }
  const float dpe = Dp[e];
  __syncthreads();

  const size_t rowE = ((size_t)b * SEQ + c * CHUNK) * DINNER + e;
  const size_t rowZ = ((size_t)b * SEQ + c * CHUNK) * (2 * DINNER) + DINNER + e;
  float dv = bf2f(d16[rowE]), xv = bf2f(xc16[rowE]);
  float zv = bf2f(xz16[rowZ]);
  for (int t = 0; t < CHUNK; ++t) {
    float dvn = 0.f, xvn = 0.f, zvn = 0.f;
    if (t + 1 < CHUNK) {
      dvn = bf2f(d16[rowE + (size_t)(t + 1) * DINNER]);
      xvn = bf2f(xc16[rowE + (size_t)(t + 1) * DINNER]);
      zvn = bf2f(xz16[rowZ + (size_t)(t + 1) * (2 * DINNER)]);
    }
    const float dxv = dv * xv;
    float y = dpe * xv;
    #pragma unroll
    for (int n = 0; n < 16; ++n) {
      const float dA = exp2f(dv * Aen[n]);
      h[n] = dA * h[n] + dxv * sB[t][n];
      y += h[n] * sC[t][n];
    }
    const float sz = zv / (1.f + __expf(-zv));
    yz16[rowE + (size_t)t * DINNER] = f2bf(y * sz);
    dv = dvn; xv = xvn; zv = zvn;
  }
}

// ---------------------------------------------------------------------------
extern "C" void kernel_launch(void* const* d_in, const int* in_sizes, int n_in,
                              void* d_out, int out_size, void* d_ws, size_t ws_size,
                              hipStream_t stream)
{
  const float* x         = (const float*)d_in[0];
  const float* norm_w    = (const float*)d_in[1];
  const float* in_proj_w = (const float*)d_in[2];
  const float* conv_w    = (const float*)d_in[3];
  const float* conv_b    = (const float*)d_in[4];
  const float* x_proj_w  = (const float*)d_in[5];
  const float* dt_proj_w = (const float*)d_in[6];
  const float* dt_proj_b = (const float*)d_in[7];
  const float* A_log     = (const float*)d_in[8];
  const float* D_param   = (const float*)d_in[9];
  const float* out_proj_w= (const float*)d_in[10];
  float* out = (float*)d_out;

  // Workspace (float offsets), total 20.25M floats = 81 MB of the 256 MB ws.
  // All regions DISJOINT except partO, which aliases xz16 (xz16 dead after
  // scanC; partO written step 9, consumed step 10, before next layer's
  // step 1 rewrites xz16).
  const size_t M = 1024 * 1024;
  float* ws = (float*)d_ws;
  ushort_t* w16i_all = (ushort_t*)ws;                 // [0,4M)    persistent
  ushort_t* w16o_all = (ushort_t*)(ws + 4 * M);       // [4M,6M)   persistent
  ushort_t* xpw16_all= (ushort_t*)(ws + 6 * M);       // 192K fl   persistent
  ushort_t* dtw16_all= (ushort_t*)(ws + 6 * M + 196608); // 128K fl persistent
  float* dbcBC    = ws + 6 * M + 327680;              // 64K fl
  ushort_t* dl16  = (ushort_t*)(ws + 6 * M + 393216); // 64K fl
  ushort_t* xz16  = (ushort_t*)(ws + 6 * M + 524288); // [6.5M,10.5M)
  ushort_t* partO = xz16;                             // alias (time-disjoint)
  ushort_t* xc16  = (ushort_t*)(ws + 10 * M + 524288);// [10.5M,12.5M)
  ushort_t* d16   = (ushort_t*)(ws + 12 * M + 524288);// [12.5M,14.5M)
  ushort_t* P16   = (ushort_t*)(ws + 14 * M + 524288);// [14.5M,15.5M)
  ushort_t* H16   = (ushort_t*)(ws + 15 * M + 524288);// [15.5M,16.5M)
  ushort_t* yz16  = (ushort_t*)(ws + 16 * M + 524288);// [16.5M,18.5M)
  ushort_t* h16   = (ushort_t*)(ws + 18 * M + 524288);// [18.5M,19.5M)
  ushort_t* partX = (ushort_t*)(ws + 19 * M + 524288);// [19.5M,20.25M)

  // Upfront: cast ALL layers' weights to bf16 (weights are layer-contiguous).
  cast_bf16_kernel<<<NLAYERS * 2 * DINNER * DMODEL / 1024, 256, 0, stream>>>(
      in_proj_w, w16i_all);
  cast_bf16_kernel<<<NLAYERS * DMODEL * DINNER / 1024, 256, 0, stream>>>(
      out_proj_w, w16o_all);
  cast_bf16_kernel<<<NLAYERS * 96 * DINNER / 1024, 256, 0, stream>>>(
      x_proj_w, xpw16_all);
  cast_bf16_kernel<<<NLAYERS * DINNER * DTRANK / 1024, 256, 0, stream>>>(
      dt_proj_w, dtw16_all);

  // Init: residual = x, h16 = rms(x) * norm_w[0]
  init_rms_kernel<<<ROWS, 256, 0, stream>>>(x, norm_w, out, h16);

  for (int layer = 0; layer < NLAYERS; ++layer) {
    const float* cw  = conv_w     + (size_t)layer * DINNER * DCONV;
    const float* cb  = conv_b     + (size_t)layer * DINNER;
    const float* dtb = dt_proj_b  + (size_t)layer * DINNER;
    const float* Al  = A_log      + (size_t)layer * DINNER * DSTATE;
    const float* Dpp = D_param    + (size_t)layer * DINNER;
    const ushort_t* w16i  = w16i_all  + (size_t)layer * 2 * DINNER * DMODEL;
    const ushort_t* w16o  = w16o_all  + (size_t)layer * DMODEL * DINNER;
    const ushort_t* xpw16 = xpw16_all + (size_t)layer * 96 * DINNER;
    const ushort_t* dtw16 = dtw16_all + (size_t)layer * DINNER * DTRANK;

    // 1. xz = h @ in_w^T (bf16 MFMA) -> bf16 xz16 (both halves)
    gemm_bf16_kernel<2>
        <<<dim3(2 * DINNER / 128, ROWS / 128), 256, 0, stream>>>(
            h16, w16i, xz16, nullptr, DMODEL, DMODEL, DMODEL, 2 * DINNER);

    // 2. xc16 = bf16(silu(causal_conv(xz16[:, :DINNER]) + cb))
    conv_silu_kernel<<<(size_t)ROWS * DINNER / 8 / 256, 256, 0, stream>>>(
        xz16, cw, cb, xc16);

    // 3+4. dbc = xc @ xpw^T  (bf16 MFMA split-K + reduce)
    xproj_mfma_kernel<<<dim3(KSPLIT, ROWS / 128), 256, 0, stream>>>(
        xc16, xpw16, partX);
    xproj_reduce_kernel<<<ROWS * 96 / 256, 256, 0, stream>>>(
        partX, dbcBC, dl16);

    // 5. delta = softplus(dl16 @ dtw^T + dtb) -> bf16 d16
    gemm_bf16_kernel<3>
        <<<dim3(DINNER / 128, ROWS / 128), 256, 0, stream>>>(
            dl16, dtw16, d16, dtb, DTRANK, DTRANK, DTRANK, DINNER);

    // 6-8. chunked selective scan + D skip + z gate -> yz16
    scan_chunk_kernel<<<dim3(DINNER / 256, BATCH * NCHUNK), 256, 0, stream>>>(
        d16, xc16, dbcBC, Al, P16, H16);
    scan_combine_kernel<<<BATCH * DINNER * 16 / 256, 256, 0, stream>>>(
        P16, H16);
    scan_out_kernel<<<dim3(DINNER / 256, BATCH * NCHUNK), 256, 0, stream>>>(
        d16, xc16, dbcBC, xz16, Al, Dpp, H16, yz16);

    // 9. out_proj split-K (bf16 partials; partO aliases xz16 - now dead)
    outproj_splitk_kernel
        <<<dim3(DMODEL / 128, ROWS / 128, KSO), 256, 0, stream>>>(
            yz16, w16o, partO);

    // 10. residual += sum_z partO[z]; fuse next layer's rmsnorm
    if (layer + 1 < NLAYERS) {
      outproj_reduce_rms_kernel<true><<<ROWS, 256, 0, stream>>>(
          partO, norm_w + (size_t)(layer + 1) * DMODEL, out, h16);
    } else {
      outproj_reduce_rms_kernel<false><<<ROWS, 256, 0, stream>>>(
          partO, nullptr, out, nullptr);
    }
  }
}

// Round 15
// 308.834 us; speedup vs baseline: 1.1515x; 1.1259x over previous
//
#include <hip/hip_runtime.h>
#include <hip/hip_bf16.h>

// Problem constants
#define BATCH   2
#define SEQ     1024
#define DMODEL  1024
#define DINNER  2048
#define DSTATE  16
#define DTRANK  64
#define DCONV   4
#define NLAYERS 2
#define ROWS    (BATCH*SEQ)        // 2048 (b,l) rows
#define NCHUNK  32
#define CHUNK   32                 // SEQ / NCHUNK
#define KSPLIT  8
#define KSLICE  (DINNER / KSPLIT)  // 256  (x_proj)
#define KSO     4
#define KSLICE_O (DINNER / KSO)    // 512  (out_proj)
#define LOG2E   1.44269504088896f

typedef unsigned short ushort_t;
typedef __attribute__((ext_vector_type(8))) short short8;
typedef __attribute__((ext_vector_type(4))) float f32x4;

// fp32 -> bf16 round-to-nearest-even
__device__ __forceinline__ ushort_t f2bf(float f) {
  union { float f; unsigned u; } v; v.f = f;
  unsigned r = v.u + 0x7fffu + ((v.u >> 16) & 1u);
  return (ushort_t)(r >> 16);
}
__device__ __forceinline__ float bf2f(ushort_t h) {
  union { unsigned u; float f; } v; v.u = ((unsigned)h) << 16;
  return v.f;
}
// native v_exp_f32 (2^x) — NOT libm exp2f (which is the slow precise path;
// R13 lesson: exp2f cost ~+30us vs __expf; this builtin is the fast one).
__device__ __forceinline__ float fexp2(float x) {
  return __builtin_amdgcn_exp2f(x);
}

// async global->LDS 16B
__device__ __forceinline__ void g2lds16(const ushort_t* g, ushort_t* l) {
  __builtin_amdgcn_global_load_lds(
      (const __attribute__((address_space(1))) void*)g,
      (__attribute__((address_space(3))) void*)l, 16, 0, 0);
}

// XCD-aware bijective block swizzle (requires gridDim.x*gridDim.y % 8 == 0).
__device__ __forceinline__ void xcd_swz(int& bx, int& by) {
  const int nx = gridDim.x, nwg = nx * gridDim.y;
  int id = by * nx + bx;
  const int q = nwg >> 3;
  id = (id & 7) * q + (id >> 3);
  bx = id % nx; by = id / nx;
}

// LDS quarter-swizzle (store quarter q of row r at q ^ ((r>>1)&3)):
#define STG_Q(tid) (((tid) & 3) ^ (((tid) >> 3) & 3))
#define LDQ(lane)  ((((lane) >> 4) ^ (((lane) >> 1) & 3)) * 8)

// ---------------------------------------------------------------------------
// cast fp32 -> bf16, 4 elems/thread
__global__ __launch_bounds__(256) void cast_bf16_kernel(
    const float* __restrict__ in, ushort_t* __restrict__ out)
{
  const int i = blockIdx.x * 256 + threadIdx.x;
  const float4 v = reinterpret_cast<const float4*>(in)[i];
  ushort4 o;
  o.x = f2bf(v.x); o.y = f2bf(v.y); o.z = f2bf(v.z); o.w = f2bf(v.w);
  reinterpret_cast<ushort4*>(out)[i] = o;
}

// ---------------------------------------------------------------------------
// init: out = x; h16 = bf16(rms(x) * w).  One block per row, 4 elems/thread.
__global__ __launch_bounds__(256) void init_rms_kernel(
    const float* __restrict__ x, const float* __restrict__ w,
    float* __restrict__ out, ushort_t* __restrict__ h16)
{
  const int row = blockIdx.x, t = threadIdx.x;
  const size_t base = (size_t)row * DMODEL + 4 * t;
  const float4 s = *reinterpret_cast<const float4*>(&x[base]);
  *reinterpret_cast<float4*>(&out[base]) = s;
  float ss = s.x * s.x + s.y * s.y + s.z * s.z + s.w * s.w;
  #pragma unroll
  for (int m = 1; m < 64; m <<= 1) ss += __shfl_xor(ss, m);
  __shared__ float red[4];
  if ((t & 63) == 0) red[t >> 6] = ss;
  __syncthreads();
  const float tot = red[0] + red[1] + red[2] + red[3];
  const float scale = rsqrtf(tot * (1.f / DMODEL) + 1e-5f);
  const float4 w4 = *reinterpret_cast<const float4*>(&w[4 * t]);
  ushort4 o;
  o.x = f2bf(s.x * scale * w4.x); o.y = f2bf(s.y * scale * w4.y);
  o.z = f2bf(s.z * scale * w4.z); o.w = f2bf(s.w * scale * w4.w);
  *reinterpret_cast<ushort4*>(&h16[base]) = o;
}

// ---------------------------------------------------------------------------
// bf16 MFMA GEMM: D[M][N] = A[M][K] * B[N][K]^T, bf16 output to C2.
// BM=BN=128, BK=32, 256 threads = 4 waves (2x2), 64x64 per wave.
// MODE 2: C2 = bf16(acc).  MODE 3: C2 = bf16(softplus(acc + bias[col])).
template<int MODE>
__global__ __launch_bounds__(256) void gemm_bf16_kernel(
    const ushort_t* __restrict__ A, const ushort_t* __restrict__ B,
    ushort_t* __restrict__ C2, const float* __restrict__ bias,
    int K, int lda, int ldb, int ldc)
{
  __shared__ __align__(16) ushort_t As[128 * 32];
  __shared__ __align__(16) ushort_t Bs[128 * 32];
  const int tid = threadIdx.x;
  const int lane = tid & 63, wid = tid >> 6;
  const int wr = wid >> 1, wc = wid & 1;
  int bx = blockIdx.x, by = blockIdx.y;
  xcd_swz(bx, by);
  const int row0 = by * 128, col0 = bx * 128;

  const int sq = STG_Q(tid) * 8;
  const ushort_t* ga0 = A + (size_t)(row0 + (tid >> 2)) * lda + sq;
  const ushort_t* ga1 = A + (size_t)(row0 + 64 + (tid >> 2)) * lda + sq;
  const ushort_t* gb0 = B + (size_t)(col0 + (tid >> 2)) * ldb + sq;
  const ushort_t* gb1 = B + (size_t)(col0 + 64 + (tid >> 2)) * ldb + sq;
  ushort_t* la0 = &As[tid * 8];
  ushort_t* la1 = &As[(256 + tid) * 8];
  ushort_t* lb0 = &Bs[tid * 8];
  ushort_t* lb1 = &Bs[(256 + tid) * 8];

  const int lk = LDQ(lane);
  const int lr16 = lane & 15;

  f32x4 acc[4][4] = {};

  for (int kb = 0; kb < K; kb += 32) {
    g2lds16(ga0 + kb, la0);
    g2lds16(ga1 + kb, la1);
    g2lds16(gb0 + kb, lb0);
    g2lds16(gb1 + kb, lb1);
    __syncthreads();

    short8 af[4], bfr[4];
    #pragma unroll
    for (int i = 0; i < 4; ++i)
      af[i] = *reinterpret_cast<const short8*>(
          &As[(wr * 64 + i * 16 + lr16) * 32 + lk]);
    #pragma unroll
    for (int j = 0; j < 4; ++j)
      bfr[j] = *reinterpret_cast<const short8*>(
          &Bs[(wc * 64 + j * 16 + lr16) * 32 + lk]);
    #pragma unroll
    for (int i = 0; i < 4; ++i)
      #pragma unroll
      for (int j = 0; j < 4; ++j)
        acc[i][j] = __builtin_amdgcn_mfma_f32_16x16x32_bf16(
            af[i], bfr[j], acc[i][j], 0, 0, 0);
    __syncthreads();
  }

  // C/D layout: col = lane&15, row = (lane>>4)*4 + reg
  const int cr = (lane >> 4) * 4;
  #pragma unroll
  for (int i = 0; i < 4; ++i) {
    #pragma unroll
    for (int j = 0; j < 4; ++j) {
      const int col = col0 + wc * 64 + j * 16 + lr16;
      #pragma unroll
      for (int r = 0; r < 4; ++r) {
        const int row = row0 + wr * 64 + i * 16 + cr + r;
        float v = acc[i][j][r];
        if (MODE == 3) {
          v += bias[col];
          v = (v > 20.f) ? v : log1pf(__expf(v));
        }
        C2[(size_t)row * ldc + col] = f2bf(v);
      }
    }
  }
}

// ---------------------------------------------------------------------------
// out_proj split-K: partial[z] = yz16 @ ow16^T over K slice z (bf16 partials).
__global__ __launch_bounds__(256) void outproj_splitk_kernel(
    const ushort_t* __restrict__ A,    // (ROWS, DINNER)
    const ushort_t* __restrict__ B,    // (DMODEL, DINNER)
    ushort_t* __restrict__ partial)    // (KSO, ROWS, DMODEL) bf16
{
  __shared__ __align__(16) ushort_t As[128 * 32];
  __shared__ __align__(16) ushort_t Bs[128 * 32];
  const int tid = threadIdx.x;
  const int lane = tid & 63, wid = tid >> 6;
  const int wr = wid >> 1, wc = wid & 1;
  int bx = blockIdx.x, by = blockIdx.y;
  xcd_swz(bx, by);
  const int row0 = by * 128, col0 = bx * 128;
  const int k0 = blockIdx.z * KSLICE_O;

  const int sq = STG_Q(tid) * 8;
  const ushort_t* ga0 = A + (size_t)(row0 + (tid >> 2)) * DINNER + k0 + sq;
  const ushort_t* ga1 = A + (size_t)(row0 + 64 + (tid >> 2)) * DINNER + k0 + sq;
  const ushort_t* gb0 = B + (size_t)(col0 + (tid >> 2)) * DINNER + k0 + sq;
  const ushort_t* gb1 = B + (size_t)(col0 + 64 + (tid >> 2)) * DINNER + k0 + sq;
  ushort_t* la0 = &As[tid * 8];
  ushort_t* la1 = &As[(256 + tid) * 8];
  ushort_t* lb0 = &Bs[tid * 8];
  ushort_t* lb1 = &Bs[(256 + tid) * 8];

  const int lk = LDQ(lane);
  const int lr16 = lane & 15;

  f32x4 acc[4][4] = {};

  for (int kb = 0; kb < KSLICE_O; kb += 32) {
    g2lds16(ga0 + kb, la0);
    g2lds16(ga1 + kb, la1);
    g2lds16(gb0 + kb, lb0);
    g2lds16(gb1 + kb, lb1);
    __syncthreads();

    short8 af[4], bfr[4];
    #pragma unroll
    for (int i = 0; i < 4; ++i)
      af[i] = *reinterpret_cast<const short8*>(
          &As[(wr * 64 + i * 16 + lr16) * 32 + lk]);
    #pragma unroll
    for (int j = 0; j < 4; ++j)
      bfr[j] = *reinterpret_cast<const short8*>(
          &Bs[(wc * 64 + j * 16 + lr16) * 32 + lk]);
    #pragma unroll
    for (int i = 0; i < 4; ++i)
      #pragma unroll
      for (int j = 0; j < 4; ++j)
        acc[i][j] = __builtin_amdgcn_mfma_f32_16x16x32_bf16(
            af[i], bfr[j], acc[i][j], 0, 0, 0);
    __syncthreads();
  }

  ushort_t* Cz = partial + (size_t)blockIdx.z * ROWS * DMODEL;
  const int cr = (lane >> 4) * 4;
  #pragma unroll
  for (int i = 0; i < 4; ++i) {
    #pragma unroll
    for (int j = 0; j < 4; ++j) {
      const int col = col0 + wc * 64 + j * 16 + lr16;
      #pragma unroll
      for (int r = 0; r < 4; ++r) {
        const int row = row0 + wr * 64 + i * 16 + cr + r;
        Cz[(size_t)row * DMODEL + col] = f2bf(acc[i][j][r]);
      }
    }
  }
}

// ---------------------------------------------------------------------------
// out += sum_z partial[z]; if RMS, also emit h16 = bf16(rms(out_row) * nw).
// One block per row (256 threads x 4 elems = DMODEL).
template<bool RMS>
__global__ __launch_bounds__(256) void outproj_reduce_rms_kernel(
    const ushort_t* __restrict__ partial, const float* __restrict__ nw,
    float* __restrict__ out, ushort_t* __restrict__ h16)
{
  const int row = blockIdx.x, t = threadIdx.x;
  const size_t base = (size_t)row * DMODEL + 4 * t;
  float4 s = *reinterpret_cast<float4*>(&out[base]);
  #pragma unroll
  for (int z = 0; z < KSO; ++z) {
    const ushort4 p = *reinterpret_cast<const ushort4*>(
        &partial[(size_t)z * ROWS * DMODEL + base]);
    s.x += bf2f(p.x); s.y += bf2f(p.y); s.z += bf2f(p.z); s.w += bf2f(p.w);
  }
  *reinterpret_cast<float4*>(&out[base]) = s;
  if (RMS) {
    float ss = s.x * s.x + s.y * s.y + s.z * s.z + s.w * s.w;
    #pragma unroll
    for (int m = 1; m < 64; m <<= 1) ss += __shfl_xor(ss, m);
    __shared__ float red[4];
    if ((t & 63) == 0) red[t >> 6] = ss;
    __syncthreads();
    const float tot = red[0] + red[1] + red[2] + red[3];
    const float scale = rsqrtf(tot * (1.f / DMODEL) + 1e-5f);
    const float4 w4 = *reinterpret_cast<const float4*>(&nw[4 * t]);
    ushort4 o;
    o.x = f2bf(s.x * scale * w4.x); o.y = f2bf(s.y * scale * w4.y);
    o.z = f2bf(s.z * scale * w4.z); o.w = f2bf(s.w * scale * w4.w);
    *reinterpret_cast<ushort4*>(&h16[base]) = o;
  }
}

// ---------------------------------------------------------------------------
// x_proj MFMA split-K: partial[kz] = xc16 @ xpw16^T over K slice kz (bf16).
__global__ __launch_bounds__(256) void xproj_mfma_kernel(
    const ushort_t* __restrict__ A,    // (ROWS, DINNER) bf16 xc
    const ushort_t* __restrict__ B,    // (96, DINNER) bf16 xpw
    ushort_t* __restrict__ partial)    // (KSPLIT, ROWS, 96) bf16
{
  __shared__ __align__(16) ushort_t As[128 * 32];
  __shared__ __align__(16) ushort_t Bs[96 * 32];
  const int tid = threadIdx.x;
  const int lane = tid & 63, wid = tid >> 6;
  int bx = blockIdx.x, by = blockIdx.y;
  xcd_swz(bx, by);
  const int kz = bx, row0 = by * 128;
  const int k0 = kz * KSLICE;

  const int sq = STG_Q(tid) * 8;
  const ushort_t* ga0 = A + (size_t)(row0 + (tid >> 2)) * DINNER + k0 + sq;
  const ushort_t* ga1 = A + (size_t)(row0 + 64 + (tid >> 2)) * DINNER + k0 + sq;
  const ushort_t* gb0 = B + (size_t)(tid >> 2) * DINNER + k0 + sq;
  const ushort_t* gb1 = B + (size_t)(64 + (tid >> 2)) * DINNER + k0 + sq; // tid<128
  ushort_t* la0 = &As[tid * 8];
  ushort_t* la1 = &As[(256 + tid) * 8];
  ushort_t* lb0 = &Bs[tid * 8];
  ushort_t* lb1 = &Bs[(256 + tid) * 8];                                  // tid<128

  const int lk = LDQ(lane);
  const int lr16 = lane & 15;

  f32x4 acc[2][6] = {};

  for (int kb = 0; kb < KSLICE; kb += 32) {
    g2lds16(ga0 + kb, la0);
    g2lds16(ga1 + kb, la1);
    g2lds16(gb0 + kb, lb0);
    if (tid < 128) g2lds16(gb1 + kb, lb1);   // rows 64..95 of B
    __syncthreads();

    short8 af[2], bfr[6];
    #pragma unroll
    for (int i = 0; i < 2; ++i)
      af[i] = *reinterpret_cast<const short8*>(
          &As[(wid * 32 + i * 16 + lr16) * 32 + lk]);
    #pragma unroll
    for (int j = 0; j < 6; ++j)
      bfr[j] = *reinterpret_cast<const short8*>(
          &Bs[(j * 16 + lr16) * 32 + lk]);
    #pragma unroll
    for (int i = 0; i < 2; ++i)
      #pragma unroll
      for (int j = 0; j < 6; ++j)
        acc[i][j] = __builtin_amdgcn_mfma_f32_16x16x32_bf16(
            af[i], bfr[j], acc[i][j], 0, 0, 0);
    __syncthreads();
  }

  const int cr = (lane >> 4) * 4;
  #pragma unroll
  for (int i = 0; i < 2; ++i) {
    #pragma unroll
    for (int j = 0; j < 6; ++j) {
      const int col = j * 16 + lr16;
      #pragma unroll
      for (int r = 0; r < 4; ++r) {
        const int row = row0 + wid * 32 + i * 16 + cr + r;
        partial[((size_t)kz * ROWS + row) * 96 + col] = f2bf(acc[i][j][r]);
      }
    }
  }
}

// ---------------------------------------------------------------------------
// x_proj reduce: sum KSPLIT bf16 partials.  cols 0..63 -> bf16 dl16;
// cols 64..95 -> fp32 dbcBC[row][32] (B,C for scan).
__global__ __launch_bounds__(256) void xproj_reduce_kernel(
    const ushort_t* __restrict__ partial, float* __restrict__ dbcBC,
    ushort_t* __restrict__ dl16)
{
  const int idx = blockIdx.x * 256 + threadIdx.x;   // < ROWS*96
  const int row = idx / 96, j = idx % 96;
  float s = 0.f;
  #pragma unroll
  for (int z = 0; z < KSPLIT; ++z)
    s += bf2f(partial[(size_t)z * ROWS * 96 + idx]);
  if (j < DTRANK) dl16[row * DTRANK + j] = f2bf(s);
  else            dbcBC[row * 32 + (j - DTRANK)] = s;
}

// ---------------------------------------------------------------------------
// Depthwise causal conv (k=4) + bias + SiLU over bf16 xz; 8 channels/thread.
__global__ __launch_bounds__(256) void conv_silu_kernel(
    const ushort_t* __restrict__ xz16,  // (ROWS, 2*DINNER) conv input = cols<DINNER
    const float* __restrict__ cw, const float* __restrict__ cb,
    ushort_t* __restrict__ xc16)        // (ROWS, DINNER)
{
  const int idx = blockIdx.x * 256 + threadIdx.x;  // over ROWS*DINNER/8
  const int e0 = (idx * 8) % DINNER;
  const int bl = (idx * 8) / DINNER;
  const int l  = bl % SEQ;
  float acc[8];
  #pragma unroll
  for (int j = 0; j < 8; ++j) acc[j] = cb[e0 + j];
  float4 w4[8];
  #pragma unroll
  for (int j = 0; j < 8; ++j)
    w4[j] = *reinterpret_cast<const float4*>(&cw[(e0 + j) * DCONV]);
  #pragma unroll
  for (int k = 0; k < DCONV; ++k) {
    const int lk = l + k - (DCONV - 1);
    if (lk >= 0) {
      const short8 v = *reinterpret_cast<const short8*>(
          &xz16[(size_t)(bl + k - (DCONV - 1)) * (2 * DINNER) + e0]);
      #pragma unroll
      for (int j = 0; j < 8; ++j) {
        const float wv = (k == 0) ? w4[j].x : (k == 1) ? w4[j].y
                        : (k == 2) ? w4[j].z : w4[j].w;
        acc[j] += bf2f((ushort_t)v[j]) * wv;
      }
    }
  }
  short8 o;
  #pragma unroll
  for (int j = 0; j < 8; ++j) {
    const float v = acc[j] / (1.f + __expf(-acc[j]));
    o[j] = (short)f2bf(v);
  }
  *reinterpret_cast<short8*>(&xc16[(size_t)bl * DINNER + e0]) = o;
}

// ---------------------------------------------------------------------------
// Pass A: lane-per-(b,c,e), 16 states in registers; exp2-folded decay via
// native v_exp_f32.
__global__ __launch_bounds__(256) void scan_chunk_kernel(
    const ushort_t* __restrict__ d16,  // (ROWS, DINNER) softplus'd delta, bf16
    const ushort_t* __restrict__ xc16, // (ROWS, DINNER) bf16
    const float* __restrict__ dbcBC,   // (ROWS, 32): [0..16)=B
    const float* __restrict__ A_log,   // (DINNER, 16)
    ushort_t* __restrict__ P16,        // (BATCH, NCHUNK, DINNER, 16) bf16
    ushort_t* __restrict__ H16)        // (BATCH, NCHUNK, DINNER, 16) bf16
{
  __shared__ float sB[CHUNK][16];
  const int bc = blockIdx.y;               // b*NCHUNK + c
  const int b = bc / NCHUNK, c = bc % NCHUNK;
  const int e = blockIdx.x * 256 + threadIdx.x;
  const size_t row32 = ((size_t)b * SEQ + c * CHUNK) * 32;
  #pragma unroll
  for (int p = 0; p < (CHUNK * 16) / 256; ++p) {
    const int idx = threadIdx.x + p * 256;
    sB[idx >> 4][idx & 15] = dbcBC[row32 + (idx >> 4) * 32 + (idx & 15)];
  }
  float Aen[16];   // -exp(A_log) * log2(e)  (exp2-folded)
  #pragma unroll
  for (int q = 0; q < 4; ++q) {
    const float4 a4 = *reinterpret_cast<const float4*>(&A_log[(size_t)e * 16 + q * 4]);
    Aen[q * 4 + 0] = -__expf(a4.x) * LOG2E;
    Aen[q * 4 + 1] = -__expf(a4.y) * LOG2E;
    Aen[q * 4 + 2] = -__expf(a4.z) * LOG2E;
    Aen[q * 4 + 3] = -__expf(a4.w) * LOG2E;
  }
  __syncthreads();

  float h[16];
  #pragma unroll
  for (int n = 0; n < 16; ++n) h[n] = 0.f;
  float sd = 0.f;
  const size_t rowE = ((size_t)b * SEQ + c * CHUNK) * DINNER + e;
  float dv = bf2f(d16[rowE]), xv = bf2f(xc16[rowE]);
  for (int t = 0; t < CHUNK; ++t) {
    float dvn = 0.f, xvn = 0.f;
    if (t + 1 < CHUNK) {
      dvn = bf2f(d16[rowE + (size_t)(t + 1) * DINNER]);
      xvn = bf2f(xc16[rowE + (size_t)(t + 1) * DINNER]);
    }
    const float dxv = dv * xv;
    sd += dv;
    #pragma unroll
    for (int n = 0; n < 16; ++n) {
      const float dA = fexp2(dv * Aen[n]);
      h[n] = dA * h[n] + dxv * sB[t][n];
    }
    dv = dvn; xv = xvn;
  }
  const size_t o = ((size_t)bc * DINNER + e) * 16;
  #pragma unroll
  for (int q = 0; q < 4; ++q) {
    ushort4 pv, hv;
    pv.x = f2bf(fexp2(Aen[q * 4 + 0] * sd));
    pv.y = f2bf(fexp2(Aen[q * 4 + 1] * sd));
    pv.z = f2bf(fexp2(Aen[q * 4 + 2] * sd));
    pv.w = f2bf(fexp2(Aen[q * 4 + 3] * sd));
    hv.x = f2bf(h[q * 4 + 0]); hv.y = f2bf(h[q * 4 + 1]);
    hv.z = f2bf(h[q * 4 + 2]); hv.w = f2bf(h[q * 4 + 3]);
    *reinterpret_cast<ushort4*>(&P16[o + q * 4]) = pv;
    *reinterpret_cast<ushort4*>(&H16[o + q * 4]) = hv;
  }
}

// ---------------------------------------------------------------------------
// Pass B: serial combine over NCHUNK summaries; one thread per (b,e,n).
__global__ __launch_bounds__(256) void scan_combine_kernel(
    const ushort_t* __restrict__ P16, ushort_t* __restrict__ H16)
{
  const int idx = blockIdx.x * 256 + threadIdx.x;   // b*(DINNER*16) + e*16 + n
  const int b = idx >> 15;
  const int en = idx & (DINNER * 16 - 1);
  const size_t base = (size_t)b * NCHUNK * DINNER * 16 + en;
  float H = 0.f;
  float P = bf2f(P16[base]), hf = bf2f(H16[base]);
  for (int c = 0; c < NCHUNK; ++c) {
    const size_t o = base + (size_t)c * DINNER * 16;
    float Pn = 0.f, hfn = 0.f;
    if (c + 1 < NCHUNK) {
      const size_t on = o + (size_t)DINNER * 16;
      Pn = bf2f(P16[on]); hfn = bf2f(H16[on]);
    }
    H16[o] = f2bf(H);
    H = P * H + hf;
    P = Pn; hf = hfn;
  }
}

// ---------------------------------------------------------------------------
// Pass C: seeded re-scan fused with C-dot, D skip, z gate -> bf16 yz.
__global__ __launch_bounds__(256) void scan_out_kernel(
    const ushort_t* __restrict__ d16,  // (ROWS, DINNER) bf16
    const ushort_t* __restrict__ xc16, // (ROWS, DINNER) bf16
    const float* __restrict__ dbcBC,   // (ROWS, 32)
    const ushort_t* __restrict__ xz16, // (ROWS, 2*DINNER): z at col DINNER+e
    const float* __restrict__ A_log,   // (DINNER, 16)
    const float* __restrict__ Dp,      // (DINNER)
    const ushort_t* __restrict__ H16,  // [b][c][e][n] seeds (bf16)
    ushort_t* __restrict__ yz16)       // (ROWS, DINNER) bf16 out
{
  __shared__ float sB[CHUNK][16];
  __shared__ float sC[CHUNK][16];
  const int bc = blockIdx.y;
  const int b = bc / NCHUNK, c = bc % NCHUNK;
  const int e = blockIdx.x * 256 + threadIdx.x;
  const size_t row32 = ((size_t)b * SEQ + c * CHUNK) * 32;
  #pragma unroll
  for (int p = 0; p < (CHUNK * 32) / 256; ++p) {
    const int idx = threadIdx.x + p * 256;
    const int t = idx >> 5, j = idx & 31;
    const float v = dbcBC[row32 + t * 32 + j];
    if (j < 16) sB[t][j] = v; else sC[t][j - 16] = v;
  }
  float Aen[16];
  #pragma unroll
  for (int q = 0; q < 4; ++q) {
    const float4 a4 = *reinterpret_cast<const float4*>(&A_log[(size_t)e * 16 + q * 4]);
    Aen[q * 4 + 0] = -__expf(a4.x) * LOG2E;
    Aen[q * 4 + 1] = -__expf(a4.y) * LOG2E;
    Aen[q * 4 + 2] = -__expf(a4.z) * LOG2E;
    Aen[q * 4 + 3] = -__expf(a4.w) * LOG2E;
  }
  float h[16];
  const size_t oh = ((size_t)bc * DINNER + e) * 16;
  #pragma unroll
  for (int q = 0; q < 4; ++q) {
    const ushort4 hv = *reinterpret_cast<const ushort4*>(&H16[oh + q * 4]);
    h[q * 4 + 0] = bf2f(hv.x); h[q * 4 + 1] = bf2f(hv.y);
    h[q * 4 + 2] = bf2f(hv.z); h[q * 4 + 3] = bf2f(hv.w);
  }
  const float dpe = Dp[e];
  __syncthreads();

  const size_t rowE = ((size_t)b * SEQ + c * CHUNK) * DINNER + e;
  const size_t rowZ = ((size_t)b * SEQ + c * CHUNK) * (2 * DINNER) + DINNER + e;
  float dv = bf2f(d16[rowE]), xv = bf2f(xc16[rowE]);
  float zv = bf2f(xz16[rowZ]);
  for (int t = 0; t < CHUNK; ++t) {
    float dvn = 0.f, xvn = 0.f, zvn = 0.f;
    if (t + 1 < CHUNK) {
      dvn = bf2f(d16[rowE + (size_t)(t + 1) * DINNER]);
      xvn = bf2f(xc16[rowE + (size_t)(t + 1) * DINNER]);
      zvn = bf2f(xz16[rowZ + (size_t)(t + 1) * (2 * DINNER)]);
    }
    const float dxv = dv * xv;
    float y = dpe * xv;
    #pragma unroll
    for (int n = 0; n < 16; ++n) {
      const float dA = fexp2(dv * Aen[n]);
      h[n] = dA * h[n] + dxv * sB[t][n];
      y += h[n] * sC[t][n];
    }
    const float sz = zv / (1.f + __expf(-zv));
    yz16[rowE + (size_t)t * DINNER] = f2bf(y * sz);
    dv = dvn; xv = xvn; zv = zvn;
  }
}

// ---------------------------------------------------------------------------
extern "C" void kernel_launch(void* const* d_in, const int* in_sizes, int n_in,
                              void* d_out, int out_size, void* d_ws, size_t ws_size,
                              hipStream_t stream)
{
  const float* x         = (const float*)d_in[0];
  const float* norm_w    = (const float*)d_in[1];
  const float* in_proj_w = (const float*)d_in[2];
  const float* conv_w    = (const float*)d_in[3];
  const float* conv_b    = (const float*)d_in[4];
  const float* x_proj_w  = (const float*)d_in[5];
  const float* dt_proj_w = (const float*)d_in[6];
  const float* dt_proj_b = (const float*)d_in[7];
  const float* A_log     = (const float*)d_in[8];
  const float* D_param   = (const float*)d_in[9];
  const float* out_proj_w= (const float*)d_in[10];
  float* out = (float*)d_out;

  // Workspace (float offsets), total 20.25M floats = 81 MB of the 256 MB ws.
  // All regions DISJOINT except partO, which aliases xz16 (xz16 dead after
  // scanC; partO written step 9, consumed step 10, before next layer's
  // step 1 rewrites xz16).
  const size_t M = 1024 * 1024;
  float* ws = (float*)d_ws;
  ushort_t* w16i_all = (ushort_t*)ws;                 // [0,4M)    persistent
  ushort_t* w16o_all = (ushort_t*)(ws + 4 * M);       // [4M,6M)   persistent
  ushort_t* xpw16_all= (ushort_t*)(ws + 6 * M);       // 192K fl   persistent
  ushort_t* dtw16_all= (ushort_t*)(ws + 6 * M + 196608); // 128K fl persistent
  float* dbcBC    = ws + 6 * M + 327680;              // 64K fl
  ushort_t* dl16  = (ushort_t*)(ws + 6 * M + 393216); // 64K fl
  ushort_t* xz16  = (ushort_t*)(ws + 6 * M + 524288); // [6.5M,10.5M)
  ushort_t* partO = xz16;                             // alias (time-disjoint)
  ushort_t* xc16  = (ushort_t*)(ws + 10 * M + 524288);// [10.5M,12.5M)
  ushort_t* d16   = (ushort_t*)(ws + 12 * M + 524288);// [12.5M,14.5M)
  ushort_t* P16   = (ushort_t*)(ws + 14 * M + 524288);// [14.5M,15.5M)
  ushort_t* H16   = (ushort_t*)(ws + 15 * M + 524288);// [15.5M,16.5M)
  ushort_t* yz16  = (ushort_t*)(ws + 16 * M + 524288);// [16.5M,18.5M)
  ushort_t* h16   = (ushort_t*)(ws + 18 * M + 524288);// [18.5M,19.5M)
  ushort_t* partX = (ushort_t*)(ws + 19 * M + 524288);// [19.5M,20.25M)

  // Upfront: cast ALL layers' weights to bf16 (weights are layer-contiguous).
  cast_bf16_kernel<<<NLAYERS * 2 * DINNER * DMODEL / 1024, 256, 0, stream>>>(
      in_proj_w, w16i_all);
  cast_bf16_kernel<<<NLAYERS * DMODEL * DINNER / 1024, 256, 0, stream>>>(
      out_proj_w, w16o_all);
  cast_bf16_kernel<<<NLAYERS * 96 * DINNER / 1024, 256, 0, stream>>>(
      x_proj_w, xpw16_all);
  cast_bf16_kernel<<<NLAYERS * DINNER * DTRANK / 1024, 256, 0, stream>>>(
      dt_proj_w, dtw16_all);

  // Init: residual = x, h16 = rms(x) * norm_w[0]
  init_rms_kernel<<<ROWS, 256, 0, stream>>>(x, norm_w, out, h16);

  for (int layer = 0; layer < NLAYERS; ++layer) {
    const float* cw  = conv_w     + (size_t)layer * DINNER * DCONV;
    const float* cb  = conv_b     + (size_t)layer * DINNER;
    const float* dtb = dt_proj_b  + (size_t)layer * DINNER;
    const float* Al  = A_log      + (size_t)layer * DINNER * DSTATE;
    const float* Dpp = D_param    + (size_t)layer * DINNER;
    const ushort_t* w16i  = w16i_all  + (size_t)layer * 2 * DINNER * DMODEL;
    const ushort_t* w16o  = w16o_all  + (size_t)layer * DMODEL * DINNER;
    const ushort_t* xpw16 = xpw16_all + (size_t)layer * 96 * DINNER;
    const ushort_t* dtw16 = dtw16_all + (size_t)layer * DINNER * DTRANK;

    // 1. xz = h @ in_w^T (bf16 MFMA) -> bf16 xz16 (both halves)
    gemm_bf16_kernel<2>
        <<<dim3(2 * DINNER / 128, ROWS / 128), 256, 0, stream>>>(
            h16, w16i, xz16, nullptr, DMODEL, DMODEL, DMODEL, 2 * DINNER);

    // 2. xc16 = bf16(silu(causal_conv(xz16[:, :DINNER]) + cb))
    conv_silu_kernel<<<(size_t)ROWS * DINNER / 8 / 256, 256, 0, stream>>>(
        xz16, cw, cb, xc16);

    // 3+4. dbc = xc @ xpw^T  (bf16 MFMA split-K + reduce)
    xproj_mfma_kernel<<<dim3(KSPLIT, ROWS / 128), 256, 0, stream>>>(
        xc16, xpw16, partX);
    xproj_reduce_kernel<<<ROWS * 96 / 256, 256, 0, stream>>>(
        partX, dbcBC, dl16);

    // 5. delta = softplus(dl16 @ dtw^T + dtb) -> bf16 d16
    gemm_bf16_kernel<3>
        <<<dim3(DINNER / 128, ROWS / 128), 256, 0, stream>>>(
            dl16, dtw16, d16, dtb, DTRANK, DTRANK, DTRANK, DINNER);

    // 6-8. chunked selective scan + D skip + z gate -> yz16
    scan_chunk_kernel<<<dim3(DINNER / 256, BATCH * NCHUNK), 256, 0, stream>>>(
        d16, xc16, dbcBC, Al, P16, H16);
    scan_combine_kernel<<<BATCH * DINNER * 16 / 256, 256, 0, stream>>>(
        P16, H16);
    scan_out_kernel<<<dim3(DINNER / 256, BATCH * NCHUNK), 256, 0, stream>>>(
        d16, xc16, dbcBC, xz16, Al, Dpp, H16, yz16);

    // 9. out_proj split-K (bf16 partials; partO aliases xz16 - now dead)
    outproj_splitk_kernel
        <<<dim3(DMODEL / 128, ROWS / 128, KSO), 256, 0, stream>>>(
            yz16, w16o, partO);

    // 10. residual += sum_z partO[z]; fuse next layer's rmsnorm
    if (layer + 1 < NLAYERS) {
      outproj_reduce_rms_kernel<true><<<ROWS, 256, 0, stream>>>(
          partO, norm_w + (size_t)(layer + 1) * DMODEL, out, h16);
    } else {
      outproj_reduce_rms_kernel<false><<<ROWS, 256, 0, stream>>>(
          partO, nullptr, out, nullptr);
    }
  }
}

// Round 17
// 302.310 us; speedup vs baseline: 1.1763x; 1.0216x over previous
//
#include <hip/hip_runtime.h>
#include <hip/hip_bf16.h>

// Problem constants
#define BATCH   2
#define SEQ     1024
#define DMODEL  1024
#define DINNER  2048
#define DSTATE  16
#define DTRANK  64
#define DCONV   4
#define NLAYERS 2
#define ROWS    (BATCH*SEQ)        // 2048 (b,l) rows
#define NCHUNK  32
#define CHUNK   32                 // SEQ / NCHUNK
#define KSPLIT  8
#define KSLICE  (DINNER / KSPLIT)  // 256  (x_proj)
#define KSO     4
#define KSLICE_O (DINNER / KSO)    // 512  (out_proj)
#define LOG2E   1.44269504088896f
#define PANEL_SQ (128 * 32)        // LDS panel stride (elems), square GEMMs
#define PANEL_XB (96 * 32)         // LDS panel stride for xproj B

typedef unsigned short ushort_t;
typedef __attribute__((ext_vector_type(8))) short short8;
typedef __attribute__((ext_vector_type(4))) float f32x4;

// fp32 -> bf16 round-to-nearest-even
__device__ __forceinline__ ushort_t f2bf(float f) {
  union { float f; unsigned u; } v; v.f = f;
  unsigned r = v.u + 0x7fffu + ((v.u >> 16) & 1u);
  return (ushort_t)(r >> 16);
}
__device__ __forceinline__ float bf2f(ushort_t h) {
  union { unsigned u; float f; } v; v.u = ((unsigned)h) << 16;
  return v.f;
}
// native v_exp_f32 (2^x) — NOT libm exp2f (R13 lesson: exp2f = slow path).
__device__ __forceinline__ float fexp2(float x) {
  return __builtin_amdgcn_exp2f(x);
}

// async global->LDS 16B
__device__ __forceinline__ void g2lds16(const ushort_t* g, ushort_t* l) {
  __builtin_amdgcn_global_load_lds(
      (const __attribute__((address_space(1))) void*)g,
      (__attribute__((address_space(3))) void*)l, 16, 0, 0);
}

// XCD-aware bijective block swizzle (requires gridDim.x*gridDim.y % 8 == 0).
__device__ __forceinline__ void xcd_swz(int& bx, int& by) {
  const int nx = gridDim.x, nwg = nx * gridDim.y;
  int id = by * nx + bx;
  const int q = nwg >> 3;
  id = (id & 7) * q + (id >> 3);
  bx = id % nx; by = id / nx;
}

// LDS quarter-swizzle (store quarter q of row r at q ^ ((r>>1)&3)):
#define STG_Q(tid) (((tid) & 3) ^ (((tid) >> 3) & 3))
#define LDQ(lane)  ((((lane) >> 4) ^ (((lane) >> 1) & 3)) * 8)

// ---------------------------------------------------------------------------
// cast fp32 -> bf16, 4 elems/thread
__global__ __launch_bounds__(256) void cast_bf16_kernel(
    const float* __restrict__ in, ushort_t* __restrict__ out)
{
  const int i = blockIdx.x * 256 + threadIdx.x;
  const float4 v = reinterpret_cast<const float4*>(in)[i];
  ushort4 o;
  o.x = f2bf(v.x); o.y = f2bf(v.y); o.z = f2bf(v.z); o.w = f2bf(v.w);
  reinterpret_cast<ushort4*>(out)[i] = o;
}

// ---------------------------------------------------------------------------
// init: out = x; h16 = bf16(rms(x) * w).  One block per row, 4 elems/thread.
__global__ __launch_bounds__(256) void init_rms_kernel(
    const float* __restrict__ x, const float* __restrict__ w,
    float* __restrict__ out, ushort_t* __restrict__ h16)
{
  const int row = blockIdx.x, t = threadIdx.x;
  const size_t base = (size_t)row * DMODEL + 4 * t;
  const float4 s = *reinterpret_cast<const float4*>(&x[base]);
  *reinterpret_cast<float4*>(&out[base]) = s;
  float ss = s.x * s.x + s.y * s.y + s.z * s.z + s.w * s.w;
  #pragma unroll
  for (int m = 1; m < 64; m <<= 1) ss += __shfl_xor(ss, m);
  __shared__ float red[4];
  if ((t & 63) == 0) red[t >> 6] = ss;
  __syncthreads();
  const float tot = red[0] + red[1] + red[2] + red[3];
  const float scale = rsqrtf(tot * (1.f / DMODEL) + 1e-5f);
  const float4 w4 = *reinterpret_cast<const float4*>(&w[4 * t]);
  ushort4 o;
  o.x = f2bf(s.x * scale * w4.x); o.y = f2bf(s.y * scale * w4.y);
  o.z = f2bf(s.z * scale * w4.z); o.w = f2bf(s.w * scale * w4.w);
  *reinterpret_cast<ushort4*>(&h16[base]) = o;
}

// ---------------------------------------------------------------------------
// bf16 MFMA GEMM: D[M][N] = A[M][K] * B[N][K]^T, bf16 output to C2.
// BM=BN=128, BK=64 (two 32-wide LDS panels -> half the barriers of BK=32).
// 256 threads = 4 waves (2x2), 64x64 per wave.  K % 64 == 0.
// MODE 2: C2 = bf16(acc).  MODE 3: C2 = bf16(softplus(acc + bias[col])).
template<int MODE>
__global__ __launch_bounds__(256) void gemm_bf16_kernel(
    const ushort_t* __restrict__ A, const ushort_t* __restrict__ B,
    ushort_t* __restrict__ C2, const float* __restrict__ bias,
    int K, int lda, int ldb, int ldc)
{
  __shared__ __align__(16) ushort_t As[128 * 64];
  __shared__ __align__(16) ushort_t Bs[128 * 64];
  const int tid = threadIdx.x;
  const int lane = tid & 63, wid = tid >> 6;
  const int wr = wid >> 1, wc = wid & 1;
  int bx = blockIdx.x, by = blockIdx.y;
  xcd_swz(bx, by);
  const int row0 = by * 128, col0 = bx * 128;

  const int sq = STG_Q(tid) * 8;
  const ushort_t* ga0 = A + (size_t)(row0 + (tid >> 2)) * lda + sq;
  const ushort_t* ga1 = A + (size_t)(row0 + 64 + (tid >> 2)) * lda + sq;
  const ushort_t* gb0 = B + (size_t)(col0 + (tid >> 2)) * ldb + sq;
  const ushort_t* gb1 = B + (size_t)(col0 + 64 + (tid >> 2)) * ldb + sq;
  ushort_t* la0 = &As[tid * 8];
  ushort_t* la1 = &As[(256 + tid) * 8];
  ushort_t* lb0 = &Bs[tid * 8];
  ushort_t* lb1 = &Bs[(256 + tid) * 8];

  const int lk = LDQ(lane);
  const int lr16 = lane & 15;

  f32x4 acc[4][4] = {};

  for (int kb = 0; kb < K; kb += 64) {
    g2lds16(ga0 + kb, la0);
    g2lds16(ga1 + kb, la1);
    g2lds16(gb0 + kb, lb0);
    g2lds16(gb1 + kb, lb1);
    g2lds16(ga0 + kb + 32, la0 + PANEL_SQ);
    g2lds16(ga1 + kb + 32, la1 + PANEL_SQ);
    g2lds16(gb0 + kb + 32, lb0 + PANEL_SQ);
    g2lds16(gb1 + kb + 32, lb1 + PANEL_SQ);
    __syncthreads();

    #pragma unroll
    for (int p = 0; p < 2; ++p) {
      const int po = p * PANEL_SQ;
      short8 af[4], bfr[4];
      #pragma unroll
      for (int i = 0; i < 4; ++i)
        af[i] = *reinterpret_cast<const short8*>(
            &As[po + (wr * 64 + i * 16 + lr16) * 32 + lk]);
      #pragma unroll
      for (int j = 0; j < 4; ++j)
        bfr[j] = *reinterpret_cast<const short8*>(
            &Bs[po + (wc * 64 + j * 16 + lr16) * 32 + lk]);
      #pragma unroll
      for (int i = 0; i < 4; ++i)
        #pragma unroll
        for (int j = 0; j < 4; ++j)
          acc[i][j] = __builtin_amdgcn_mfma_f32_16x16x32_bf16(
              af[i], bfr[j], acc[i][j], 0, 0, 0);
    }
    __syncthreads();
  }

  // C/D layout: col = lane&15, row = (lane>>4)*4 + reg
  const int cr = (lane >> 4) * 4;
  #pragma unroll
  for (int i = 0; i < 4; ++i) {
    #pragma unroll
    for (int j = 0; j < 4; ++j) {
      const int col = col0 + wc * 64 + j * 16 + lr16;
      #pragma unroll
      for (int r = 0; r < 4; ++r) {
        const int row = row0 + wr * 64 + i * 16 + cr + r;
        float v = acc[i][j][r];
        if (MODE == 3) {
          v += bias[col];
          v = (v > 20.f) ? v : log1pf(__expf(v));
        }
        C2[(size_t)row * ldc + col] = f2bf(v);
      }
    }
  }
}

// ---------------------------------------------------------------------------
// out_proj split-K: partial[z] = yz16 @ ow16^T over K slice z (bf16 partials).
// BK=64 two-panel.
__global__ __launch_bounds__(256) void outproj_splitk_kernel(
    const ushort_t* __restrict__ A,    // (ROWS, DINNER)
    const ushort_t* __restrict__ B,    // (DMODEL, DINNER)
    ushort_t* __restrict__ partial)    // (KSO, ROWS, DMODEL) bf16
{
  __shared__ __align__(16) ushort_t As[128 * 64];
  __shared__ __align__(16) ushort_t Bs[128 * 64];
  const int tid = threadIdx.x;
  const int lane = tid & 63, wid = tid >> 6;
  const int wr = wid >> 1, wc = wid & 1;
  int bx = blockIdx.x, by = blockIdx.y;
  xcd_swz(bx, by);
  const int row0 = by * 128, col0 = bx * 128;
  const int k0 = blockIdx.z * KSLICE_O;

  const int sq = STG_Q(tid) * 8;
  const ushort_t* ga0 = A + (size_t)(row0 + (tid >> 2)) * DINNER + k0 + sq;
  const ushort_t* ga1 = A + (size_t)(row0 + 64 + (tid >> 2)) * DINNER + k0 + sq;
  const ushort_t* gb0 = B + (size_t)(col0 + (tid >> 2)) * DINNER + k0 + sq;
  const ushort_t* gb1 = B + (size_t)(col0 + 64 + (tid >> 2)) * DINNER + k0 + sq;
  ushort_t* la0 = &As[tid * 8];
  ushort_t* la1 = &As[(256 + tid) * 8];
  ushort_t* lb0 = &Bs[tid * 8];
  ushort_t* lb1 = &Bs[(256 + tid) * 8];

  const int lk = LDQ(lane);
  const int lr16 = lane & 15;

  f32x4 acc[4][4] = {};

  for (int kb = 0; kb < KSLICE_O; kb += 64) {
    g2lds16(ga0 + kb, la0);
    g2lds16(ga1 + kb, la1);
    g2lds16(gb0 + kb, lb0);
    g2lds16(gb1 + kb, lb1);
    g2lds16(ga0 + kb + 32, la0 + PANEL_SQ);
    g2lds16(ga1 + kb + 32, la1 + PANEL_SQ);
    g2lds16(gb0 + kb + 32, lb0 + PANEL_SQ);
    g2lds16(gb1 + kb + 32, lb1 + PANEL_SQ);
    __syncthreads();

    #pragma unroll
    for (int p = 0; p < 2; ++p) {
      const int po = p * PANEL_SQ;
      short8 af[4], bfr[4];
      #pragma unroll
      for (int i = 0; i < 4; ++i)
        af[i] = *reinterpret_cast<const short8*>(
            &As[po + (wr * 64 + i * 16 + lr16) * 32 + lk]);
      #pragma unroll
      for (int j = 0; j < 4; ++j)
        bfr[j] = *reinterpret_cast<const short8*>(
            &Bs[po + (wc * 64 + j * 16 + lr16) * 32 + lk]);
      #pragma unroll
      for (int i = 0; i < 4; ++i)
        #pragma unroll
        for (int j = 0; j < 4; ++j)
          acc[i][j] = __builtin_amdgcn_mfma_f32_16x16x32_bf16(
              af[i], bfr[j], acc[i][j], 0, 0, 0);
    }
    __syncthreads();
  }

  ushort_t* Cz = partial + (size_t)blockIdx.z * ROWS * DMODEL;
  const int cr = (lane >> 4) * 4;
  #pragma unroll
  for (int i = 0; i < 4; ++i) {
    #pragma unroll
    for (int j = 0; j < 4; ++j) {
      const int col = col0 + wc * 64 + j * 16 + lr16;
      #pragma unroll
      for (int r = 0; r < 4; ++r) {
        const int row = row0 + wr * 64 + i * 16 + cr + r;
        Cz[(size_t)row * DMODEL + col] = f2bf(acc[i][j][r]);
      }
    }
  }
}

// ---------------------------------------------------------------------------
// out += sum_z partial[z]; if RMS, also emit h16 = bf16(rms(out_row) * nw).
template<bool RMS>
__global__ __launch_bounds__(256) void outproj_reduce_rms_kernel(
    const ushort_t* __restrict__ partial, const float* __restrict__ nw,
    float* __restrict__ out, ushort_t* __restrict__ h16)
{
  const int row = blockIdx.x, t = threadIdx.x;
  const size_t base = (size_t)row * DMODEL + 4 * t;
  float4 s = *reinterpret_cast<float4*>(&out[base]);
  #pragma unroll
  for (int z = 0; z < KSO; ++z) {
    const ushort4 p = *reinterpret_cast<const ushort4*>(
        &partial[(size_t)z * ROWS * DMODEL + base]);
    s.x += bf2f(p.x); s.y += bf2f(p.y); s.z += bf2f(p.z); s.w += bf2f(p.w);
  }
  *reinterpret_cast<float4*>(&out[base]) = s;
  if (RMS) {
    float ss = s.x * s.x + s.y * s.y + s.z * s.z + s.w * s.w;
    #pragma unroll
    for (int m = 1; m < 64; m <<= 1) ss += __shfl_xor(ss, m);
    __shared__ float red[4];
    if ((t & 63) == 0) red[t >> 6] = ss;
    __syncthreads();
    const float tot = red[0] + red[1] + red[2] + red[3];
    const float scale = rsqrtf(tot * (1.f / DMODEL) + 1e-5f);
    const float4 w4 = *reinterpret_cast<const float4*>(&nw[4 * t]);
    ushort4 o;
    o.x = f2bf(s.x * scale * w4.x); o.y = f2bf(s.y * scale * w4.y);
    o.z = f2bf(s.z * scale * w4.z); o.w = f2bf(s.w * scale * w4.w);
    *reinterpret_cast<ushort4*>(&h16[base]) = o;
  }
}

// ---------------------------------------------------------------------------
// x_proj MFMA split-K: partial[kz] = xc16 @ xpw16^T over K slice kz (bf16).
// BK=64 two-panel.
__global__ __launch_bounds__(256) void xproj_mfma_kernel(
    const ushort_t* __restrict__ A,    // (ROWS, DINNER) bf16 xc
    const ushort_t* __restrict__ B,    // (96, DINNER) bf16 xpw
    ushort_t* __restrict__ partial)    // (KSPLIT, ROWS, 96) bf16
{
  __shared__ __align__(16) ushort_t As[128 * 64];
  __shared__ __align__(16) ushort_t Bs[96 * 64];
  const int tid = threadIdx.x;
  const int lane = tid & 63, wid = tid >> 6;
  int bx = blockIdx.x, by = blockIdx.y;
  xcd_swz(bx, by);
  const int kz = bx, row0 = by * 128;
  const int k0 = kz * KSLICE;

  const int sq = STG_Q(tid) * 8;
  const ushort_t* ga0 = A + (size_t)(row0 + (tid >> 2)) * DINNER + k0 + sq;
  const ushort_t* ga1 = A + (size_t)(row0 + 64 + (tid >> 2)) * DINNER + k0 + sq;
  const ushort_t* gb0 = B + (size_t)(tid >> 2) * DINNER + k0 + sq;
  const ushort_t* gb1 = B + (size_t)(64 + (tid >> 2)) * DINNER + k0 + sq; // tid<128
  ushort_t* la0 = &As[tid * 8];
  ushort_t* la1 = &As[(256 + tid) * 8];
  ushort_t* lb0 = &Bs[tid * 8];
  ushort_t* lb1 = &Bs[(256 + tid) * 8];                                  // tid<128

  const int lk = LDQ(lane);
  const int lr16 = lane & 15;

  f32x4 acc[2][6] = {};

  for (int kb = 0; kb < KSLICE; kb += 64) {
    g2lds16(ga0 + kb, la0);
    g2lds16(ga1 + kb, la1);
    g2lds16(ga0 + kb + 32, la0 + PANEL_SQ);
    g2lds16(ga1 + kb + 32, la1 + PANEL_SQ);
    g2lds16(gb0 + kb, lb0);
    g2lds16(gb0 + kb + 32, lb0 + PANEL_XB);
    if (tid < 128) {
      g2lds16(gb1 + kb, lb1);                 // rows 64..95 of B, panel 0
      g2lds16(gb1 + kb + 32, lb1 + PANEL_XB); // panel 1
    }
    __syncthreads();

    #pragma unroll
    for (int p = 0; p < 2; ++p) {
      const int poA = p * PANEL_SQ, poB = p * PANEL_XB;
      short8 af[2], bfr[6];
      #pragma unroll
      for (int i = 0; i < 2; ++i)
        af[i] = *reinterpret_cast<const short8*>(
            &As[poA + (wid * 32 + i * 16 + lr16) * 32 + lk]);
      #pragma unroll
      for (int j = 0; j < 6; ++j)
        bfr[j] = *reinterpret_cast<const short8*>(
            &Bs[poB + (j * 16 + lr16) * 32 + lk]);
      #pragma unroll
      for (int i = 0; i < 2; ++i)
        #pragma unroll
        for (int j = 0; j < 6; ++j)
          acc[i][j] = __builtin_amdgcn_mfma_f32_16x16x32_bf16(
              af[i], bfr[j], acc[i][j], 0, 0, 0);
    }
    __syncthreads();
  }

  const int cr = (lane >> 4) * 4;
  #pragma unroll
  for (int i = 0; i < 2; ++i) {
    #pragma unroll
    for (int j = 0; j < 6; ++j) {
      const int col = j * 16 + lr16;
      #pragma unroll
      for (int r = 0; r < 4; ++r) {
        const int row = row0 + wid * 32 + i * 16 + cr + r;
        partial[((size_t)kz * ROWS + row) * 96 + col] = f2bf(acc[i][j][r]);
      }
    }
  }
}

// ---------------------------------------------------------------------------
// x_proj reduce: sum KSPLIT bf16 partials.  cols 0..63 -> bf16 dl16;
// cols 64..95 -> fp32 dbcBC[row][32] (B,C for scan).
__global__ __launch_bounds__(256) void xproj_reduce_kernel(
    const ushort_t* __restrict__ partial, float* __restrict__ dbcBC,
    ushort_t* __restrict__ dl16)
{
  const int idx = blockIdx.x * 256 + threadIdx.x;   // < ROWS*96
  const int row = idx / 96, j = idx % 96;
  float s = 0.f;
  #pragma unroll
  for (int z = 0; z < KSPLIT; ++z)
    s += bf2f(partial[(size_t)z * ROWS * 96 + idx]);
  if (j < DTRANK) dl16[row * DTRANK + j] = f2bf(s);
  else            dbcBC[row * 32 + (j - DTRANK)] = s;
}

// ---------------------------------------------------------------------------
// Depthwise causal conv (k=4) + bias + SiLU over bf16 xz; 8 channels/thread.
__global__ __launch_bounds__(256) void conv_silu_kernel(
    const ushort_t* __restrict__ xz16,  // (ROWS, 2*DINNER) conv input = cols<DINNER
    const float* __restrict__ cw, const float* __restrict__ cb,
    ushort_t* __restrict__ xc16)        // (ROWS, DINNER)
{
  const int idx = blockIdx.x * 256 + threadIdx.x;  // over ROWS*DINNER/8
  const int e0 = (idx * 8) % DINNER;
  const int bl = (idx * 8) / DINNER;
  const int l  = bl % SEQ;
  float acc[8];
  #pragma unroll
  for (int j = 0; j < 8; ++j) acc[j] = cb[e0 + j];
  float4 w4[8];
  #pragma unroll
  for (int j = 0; j < 8; ++j)
    w4[j] = *reinterpret_cast<const float4*>(&cw[(e0 + j) * DCONV]);
  #pragma unroll
  for (int k = 0; k < DCONV; ++k) {
    const int lk = l + k - (DCONV - 1);
    if (lk >= 0) {
      const short8 v = *reinterpret_cast<const short8*>(
          &xz16[(size_t)(bl + k - (DCONV - 1)) * (2 * DINNER) + e0]);
      #pragma unroll
      for (int j = 0; j < 8; ++j) {
        const float wv = (k == 0) ? w4[j].x : (k == 1) ? w4[j].y
                        : (k == 2) ? w4[j].z : w4[j].w;
        acc[j] += bf2f((ushort_t)v[j]) * wv;
      }
    }
  }
  short8 o;
  #pragma unroll
  for (int j = 0; j < 8; ++j) {
    const float v = acc[j] / (1.f + __expf(-acc[j]));
    o[j] = (short)f2bf(v);
  }
  *reinterpret_cast<short8*>(&xc16[(size_t)bl * DINNER + e0]) = o;
}

// ---------------------------------------------------------------------------
// Pass A: lane-per-(b,c,e), 16 states in registers; exp2-folded decay via
// native v_exp_f32.
__global__ __launch_bounds__(256) void scan_chunk_kernel(
    const ushort_t* __restrict__ d16,  // (ROWS, DINNER) softplus'd delta, bf16
    const ushort_t* __restrict__ xc16, // (ROWS, DINNER) bf16
    const float* __restrict__ dbcBC,   // (ROWS, 32): [0..16)=B
    const float* __restrict__ A_log,   // (DINNER, 16)
    ushort_t* __restrict__ P16,        // (BATCH, NCHUNK, DINNER, 16) bf16
    ushort_t* __restrict__ H16)        // (BATCH, NCHUNK, DINNER, 16) bf16
{
  __shared__ float sB[CHUNK][16];
  const int bc = blockIdx.y;               // b*NCHUNK + c
  const int b = bc / NCHUNK, c = bc % NCHUNK;
  const int e = blockIdx.x * 256 + threadIdx.x;
  const size_t row32 = ((size_t)b * SEQ + c * CHUNK) * 32;
  #pragma unroll
  for (int p = 0; p < (CHUNK * 16) / 256; ++p) {
    const int idx = threadIdx.x + p * 256;
    sB[idx >> 4][idx & 15] = dbcBC[row32 + (idx >> 4) * 32 + (idx & 15)];
  }
  float Aen[16];   // -exp(A_log) * log2(e)  (exp2-folded)
  #pragma unroll
  for (int q = 0; q < 4; ++q) {
    const float4 a4 = *reinterpret_cast<const float4*>(&A_log[(size_t)e * 16 + q * 4]);
    Aen[q * 4 + 0] = -__expf(a4.x) * LOG2E;
    Aen[q * 4 + 1] = -__expf(a4.y) * LOG2E;
    Aen[q * 4 + 2] = -__expf(a4.z) * LOG2E;
    Aen[q * 4 + 3] = -__expf(a4.w) * LOG2E;
  }
  __syncthreads();

  float h[16];
  #pragma unroll
  for (int n = 0; n < 16; ++n) h[n] = 0.f;
  float sd = 0.f;
  const size_t rowE = ((size_t)b * SEQ + c * CHUNK) * DINNER + e;
  float dv = bf2f(d16[rowE]), xv = bf2f(xc16[rowE]);
  for (int t = 0; t < CHUNK; ++t) {
    float dvn = 0.f, xvn = 0.f;
    if (t + 1 < CHUNK) {
      dvn = bf2f(d16[rowE + (size_t)(t + 1) * DINNER]);
      xvn = bf2f(xc16[rowE + (size_t)(t + 1) * DINNER]);
    }
    const float dxv = dv * xv;
    sd += dv;
    #pragma unroll
    for (int n = 0; n < 16; ++n) {
      const float dA = fexp2(dv * Aen[n]);
      h[n] = dA * h[n] + dxv * sB[t][n];
    }
    dv = dvn; xv = xvn;
  }
  const size_t o = ((size_t)bc * DINNER + e) * 16;
  #pragma unroll
  for (int q = 0; q < 4; ++q) {
    ushort4 pv, hv;
    pv.x = f2bf(fexp2(Aen[q * 4 + 0] * sd));
    pv.y = f2bf(fexp2(Aen[q * 4 + 1] * sd));
    pv.z = f2bf(fexp2(Aen[q * 4 + 2] * sd));
    pv.w = f2bf(fexp2(Aen[q * 4 + 3] * sd));
    hv.x = f2bf(h[q * 4 + 0]); hv.y = f2bf(h[q * 4 + 1]);
    hv.z = f2bf(h[q * 4 + 2]); hv.w = f2bf(h[q * 4 + 3]);
    *reinterpret_cast<ushort4*>(&P16[o + q * 4]) = pv;
    *reinterpret_cast<ushort4*>(&H16[o + q * 4]) = hv;
  }
}

// ---------------------------------------------------------------------------
// Pass B: serial combine over NCHUNK summaries; one thread per (b,e,n).
__global__ __launch_bounds__(256) void scan_combine_kernel(
    const ushort_t* __restrict__ P16, ushort_t* __restrict__ H16)
{
  const int idx = blockIdx.x * 256 + threadIdx.x;   // b*(DINNER*16) + e*16 + n
  const int b = idx >> 15;
  const int en = idx & (DINNER * 16 - 1);
  const size_t base = (size_t)b * NCHUNK * DINNER * 16 + en;
  float H = 0.f;
  float P = bf2f(P16[base]), hf = bf2f(H16[base]);
  for (int c = 0; c < NCHUNK; ++c) {
    const size_t o = base + (size_t)c * DINNER * 16;
    float Pn = 0.f, hfn = 0.f;
    if (c + 1 < NCHUNK) {
      const size_t on = o + (size_t)DINNER * 16;
      Pn = bf2f(P16[on]); hfn = bf2f(H16[on]);
    }
    H16[o] = f2bf(H);
    H = P * H + hf;
    P = Pn; hf = hfn;
  }
}

// ---------------------------------------------------------------------------
// Pass C: seeded re-scan fused with C-dot, D skip, z gate -> bf16 yz.
__global__ __launch_bounds__(256) void scan_out_kernel(
    const ushort_t* __restrict__ d16,  // (ROWS, DINNER) bf16
    const ushort_t* __restrict__ xc16, // (ROWS, DINNER) bf16
    const float* __restrict__ dbcBC,   // (ROWS, 32)
    const ushort_t* __restrict__ xz16, // (ROWS, 2*DINNER): z at col DINNER+e
    const float* __restrict__ A_log,   // (DINNER, 16)
    const float* __restrict__ Dp,      // (DINNER)
    const ushort_t* __restrict__ H16,  // [b][c][e][n] seeds (bf16)
    ushort_t* __restrict__ yz16)       // (ROWS, DINNER) bf16 out
{
  __shared__ float sB[CHUNK][16];
  __shared__ float sC[CHUNK][16];
  const int bc = blockIdx.y;
  const int b = bc / NCHUNK, c = bc % NCHUNK;
  const int e = blockIdx.x * 256 + threadIdx.x;
  const size_t row32 = ((size_t)b * SEQ + c * CHUNK) * 32;
  #pragma unroll
  for (int p = 0; p < (CHUNK * 32) / 256; ++p) {
    const int idx = threadIdx.x + p * 256;
    const int t = idx >> 5, j = idx & 31;
    const float v = dbcBC[row32 + t * 32 + j];
    if (j < 16) sB[t][j] = v; else sC[t][j - 16] = v;
  }
  float Aen[16];
  #pragma unroll
  for (int q = 0; q < 4; ++q) {
    const float4 a4 = *reinterpret_cast<const float4*>(&A_log[(size_t)e * 16 + q * 4]);
    Aen[q * 4 + 0] = -__expf(a4.x) * LOG2E;
    Aen[q * 4 + 1] = -__expf(a4.y) * LOG2E;
    Aen[q * 4 + 2] = -__expf(a4.z) * LOG2E;
    Aen[q * 4 + 3] = -__expf(a4.w) * LOG2E;
  }
  float h[16];
  const size_t oh = ((size_t)bc * DINNER + e) * 16;
  #pragma unroll
  for (int q = 0; q < 4; ++q) {
    const ushort4 hv = *reinterpret_cast<const ushort4*>(&H16[oh + q * 4]);
    h[q * 4 + 0] = bf2f(hv.x); h[q * 4 + 1] = bf2f(hv.y);
    h[q * 4 + 2] = bf2f(hv.z); h[q * 4 + 3] = bf2f(hv.w);
  }
  const float dpe = Dp[e];
  __syncthreads();

  const size_t rowE = ((size_t)b * SEQ + c * CHUNK) * DINNER + e;
  const size_t rowZ = ((size_t)b * SEQ + c * CHUNK) * (2 * DINNER) + DINNER + e;
  float dv = bf2f(d16[rowE]), xv = bf2f(xc16[rowE]);
  float zv = bf2f(xz16[rowZ]);
  for (int t = 0; t < CHUNK; ++t) {
    float dvn = 0.f, xvn = 0.f, zvn = 0.f;
    if (t + 1 < CHUNK) {
      dvn = bf2f(d16[rowE + (size_t)(t + 1) * DINNER]);
      xvn = bf2f(xc16[rowE + (size_t)(t + 1) * DINNER]);
      zvn = bf2f(xz16[rowZ + (size_t)(t + 1) * (2 * DINNER)]);
    }
    const float dxv = dv * xv;
    float y = dpe * xv;
    #pragma unroll
    for (int n = 0; n < 16; ++n) {
      const float dA = fexp2(dv * Aen[n]);
      h[n] = dA * h[n] + dxv * sB[t][n];
      y += h[n] * sC[t][n];
    }
    const float sz = zv / (1.f + __expf(-zv));
    yz16[rowE + (size_t)t * DINNER] = f2bf(y * sz);
    dv = dvn; xv = xvn; zv = zvn;
  }
}

// ---------------------------------------------------------------------------
extern "C" void kernel_launch(void* const* d_in, const int* in_sizes, int n_in,
                              void* d_out, int out_size, void* d_ws, size_t ws_size,
                              hipStream_t stream)
{
  const float* x         = (const float*)d_in[0];
  const float* norm_w    = (const float*)d_in[1];
  const float* in_proj_w = (const float*)d_in[2];
  const float* conv_w    = (const float*)d_in[3];
  const float* conv_b    = (const float*)d_in[4];
  const float* x_proj_w  = (const float*)d_in[5];
  const float* dt_proj_w = (const float*)d_in[6];
  const float* dt_proj_b = (const float*)d_in[7];
  const float* A_log     = (const float*)d_in[8];
  const float* D_param   = (const float*)d_in[9];
  const float* out_proj_w= (const float*)d_in[10];
  float* out = (float*)d_out;

  // Workspace (float offsets), total 20.25M floats = 81 MB of the 256 MB ws.
  // All regions DISJOINT except partO, which aliases xz16 (xz16 dead after
  // scanC; partO written step 9, consumed step 10, before next layer's
  // step 1 rewrites xz16).
  const size_t M = 1024 * 1024;
  float* ws = (float*)d_ws;
  ushort_t* w16i_all = (ushort_t*)ws;                 // [0,4M)    persistent
  ushort_t* w16o_all = (ushort_t*)(ws + 4 * M);       // [4M,6M)   persistent
  ushort_t* xpw16_all= (ushort_t*)(ws + 6 * M);       // 192K fl   persistent
  ushort_t* dtw16_all= (ushort_t*)(ws + 6 * M + 196608); // 128K fl persistent
  float* dbcBC    = ws + 6 * M + 327680;              // 64K fl
  ushort_t* dl16  = (ushort_t*)(ws + 6 * M + 393216); // 64K fl
  ushort_t* xz16  = (ushort_t*)(ws + 6 * M + 524288); // [6.5M,10.5M)
  ushort_t* partO = xz16;                             // alias (time-disjoint)
  ushort_t* xc16  = (ushort_t*)(ws + 10 * M + 524288);// [10.5M,12.5M)
  ushort_t* d16   = (ushort_t*)(ws + 12 * M + 524288);// [12.5M,14.5M)
  ushort_t* P16   = (ushort_t*)(ws + 14 * M + 524288);// [14.5M,15.5M)
  ushort_t* H16   = (ushort_t*)(ws + 15 * M + 524288);// [15.5M,16.5M)
  ushort_t* yz16  = (ushort_t*)(ws + 16 * M + 524288);// [16.5M,18.5M)
  ushort_t* h16   = (ushort_t*)(ws + 18 * M + 524288);// [18.5M,19.5M)
  ushort_t* partX = (ushort_t*)(ws + 19 * M + 524288);// [19.5M,20.25M)

  // Upfront: cast ALL layers' weights to bf16 (weights are layer-contiguous).
  cast_bf16_kernel<<<NLAYERS * 2 * DINNER * DMODEL / 1024, 256, 0, stream>>>(
      in_proj_w, w16i_all);
  cast_bf16_kernel<<<NLAYERS * DMODEL * DINNER / 1024, 256, 0, stream>>>(
      out_proj_w, w16o_all);
  cast_bf16_kernel<<<NLAYERS * 96 * DINNER / 1024, 256, 0, stream>>>(
      x_proj_w, xpw16_all);
  cast_bf16_kernel<<<NLAYERS * DINNER * DTRANK / 1024, 256, 0, stream>>>(
      dt_proj_w, dtw16_all);

  // Init: residual = x, h16 = rms(x) * norm_w[0]
  init_rms_kernel<<<ROWS, 256, 0, stream>>>(x, norm_w, out, h16);

  for (int layer = 0; layer < NLAYERS; ++layer) {
    const float* cw  = conv_w     + (size_t)layer * DINNER * DCONV;
    const float* cb  = conv_b     + (size_t)layer * DINNER;
    const float* dtb = dt_proj_b  + (size_t)layer * DINNER;
    const float* Al  = A_log      + (size_t)layer * DINNER * DSTATE;
    const float* Dpp = D_param    + (size_t)layer * DINNER;
    const ushort_t* w16i  = w16i_all  + (size_t)layer * 2 * DINNER * DMODEL;
    const ushort_t* w16o  = w16o_all  + (size_t)layer * DMODEL * DINNER;
    const ushort_t* xpw16 = xpw16_all + (size_t)layer * 96 * DINNER;
    const ushort_t* dtw16 = dtw16_all + (size_t)layer * DINNER * DTRANK;

    // 1. xz = h @ in_w^T (bf16 MFMA, BK=64) -> bf16 xz16 (both halves)
    gemm_bf16_kernel<2>
        <<<dim3(2 * DINNER / 128, ROWS / 128), 256, 0, stream>>>(
            h16, w16i, xz16, nullptr, DMODEL, DMODEL, DMODEL, 2 * DINNER);

    // 2. xc16 = bf16(silu(causal_conv(xz16[:, :DINNER]) + cb))
    conv_silu_kernel<<<(size_t)ROWS * DINNER / 8 / 256, 256, 0, stream>>>(
        xz16, cw, cb, xc16);

    // 3+4. dbc = xc @ xpw^T  (bf16 MFMA split-K + reduce)
    xproj_mfma_kernel<<<dim3(KSPLIT, ROWS / 128), 256, 0, stream>>>(
        xc16, xpw16, partX);
    xproj_reduce_kernel<<<ROWS * 96 / 256, 256, 0, stream>>>(
        partX, dbcBC, dl16);

    // 5. delta = softplus(dl16 @ dtw^T + dtb) -> bf16 d16 (single K-step)
    gemm_bf16_kernel<3>
        <<<dim3(DINNER / 128, ROWS / 128), 256, 0, stream>>>(
            dl16, dtw16, d16, dtb, DTRANK, DTRANK, DTRANK, DINNER);

    // 6-8. chunked selective scan + D skip + z gate -> yz16
    scan_chunk_kernel<<<dim3(DINNER / 256, BATCH * NCHUNK), 256, 0, stream>>>(
        d16, xc16, dbcBC, Al, P16, H16);
    scan_combine_kernel<<<BATCH * DINNER * 16 / 256, 256, 0, stream>>>(
        P16, H16);
    scan_out_kernel<<<dim3(DINNER / 256, BATCH * NCHUNK), 256, 0, stream>>>(
        d16, xc16, dbcBC, xz16, Al, Dpp, H16, yz16);

    // 9. out_proj split-K (bf16 partials; partO aliases xz16 - now dead)
    outproj_splitk_kernel
        <<<dim3(DMODEL / 128, ROWS / 128, KSO), 256, 0, stream>>>(
            yz16, w16o, partO);

    // 10. residual += sum_z partO[z]; fuse next layer's rmsnorm
    if (layer + 1 < NLAYERS) {
      outproj_reduce_rms_kernel<true><<<ROWS, 256, 0, stream>>>(
          partO, norm_w + (size_t)(layer + 1) * DMODEL, out, h16);
    } else {
      outproj_reduce_rms_kernel<false><<<ROWS, 256, 0, stream>>>(
          partO, nullptr, out, nullptr);
    }
  }
}